// Round 7
// baseline (656.191 us; speedup 1.0000x reference)
//
#include <hip/hip_runtime.h>
#include <math.h>

#define LRELU_A 0.2f
#define NEGBIG (-9.0e15f)

typedef _Float16 f16;
typedef _Float16 f16x8 __attribute__((ext_vector_type(8)));
typedef _Float16 f16x4 __attribute__((ext_vector_type(4)));
typedef float floatx4 __attribute__((ext_vector_type(4)));

__device__ __forceinline__ float rcpf(float x){ return __builtin_amdgcn_rcpf(x); }
__device__ __forceinline__ float sigm_f(float x){ return rcpf(1.0f + __expf(-x)); }
__device__ __forceinline__ float tanh_f(float x){ return 1.0f - 2.0f*rcpf(1.0f + __expf(2.0f*x)); }
__device__ __forceinline__ float sigm(float x){ return rcpf(1.0f+__expf(-x)); }
__device__ __forceinline__ f16x8 load_cvt8(const float* __restrict__ p){
    float4 a = *(const float4*)p; float4 b = *(const float4*)(p+4);
    f16x8 r; r[0]=(f16)a.x; r[1]=(f16)a.y; r[2]=(f16)a.z; r[3]=(f16)a.w;
    r[4]=(f16)b.x; r[5]=(f16)b.y; r[6]=(f16)b.z; r[7]=(f16)b.w;
    return r;
}
#define MFMA16(A,B,C) __builtin_amdgcn_mfma_f32_16x16x32_f16((A),(B),(C),0,0,0)

// ---------------------------------------------------------------------------
// prep: Wcat1 | WcatA | WT | fwT | ggW16 | bucket. 865 blocks.
// Wcat layout: rows 0..255 [Wih_rz|Whh_rz]; 256..383 [Wih_n|0]; 384..511 [0|Whh_n]
// ---------------------------------------------------------------------------
__global__ __launch_bounds__(256) void prep_kernel(
    const float* __restrict__ g1Wih, const float* __restrict__ g1Whh,
    const float* __restrict__ gaWih, const float* __restrict__ gaWhh,
    const float* __restrict__ giW,   const float* __restrict__ fw,
    const float* __restrict__ ggWih, const int* __restrict__ sec,
    f16* __restrict__ Wcat1, f16* __restrict__ WcatA,
    f16* __restrict__ WT, f16* __restrict__ fwT, f16* __restrict__ ggW16,
    int* __restrict__ memflat, int* __restrict__ cnt, int* __restrict__ base)
{
    __shared__ int cs[16], wsc[16];
    const int b = blockIdx.x, tid = threadIdx.x;
    if (b < 160){                      // Wcat1: INF=16, INFPAD=32, KTOT=160
        for (int idx = b*256+tid; idx < 512*160; idx += 160*256){
            int r = idx/160, k = idx - r*160;
            float v = 0.0f;
            if (r < 256){ if (k < 32){ if (k < 16) v = g1Wih[r*16+k]; } else v = g1Whh[r*128 + (k-32)]; }
            else if (r < 384){ if (k < 16) v = g1Wih[r*16+k]; }
            else { if (k >= 32) v = g1Whh[(r-128)*128 + (k-32)]; }
            Wcat1[idx] = (f16)v;
        }
    } else if (b < 416){               // WcatA: INF=128, KTOT=256
        for (int idx = (b-160)*256+tid; idx < 512*256; idx += 256*256){
            int r = idx >> 8, k = idx & 255;
            float v = 0.0f;
            if (r < 256){ v = (k < 128) ? gaWih[r*128+k] : gaWhh[r*128 + (k-128)]; }
            else if (r < 384){ if (k < 128) v = gaWih[r*128+k]; }
            else { if (k >= 128) v = gaWhh[(r-128)*128 + (k-128)]; }
            WcatA[idx] = (f16)v;
        }
    } else if (b < 480){               // WT = giW^T (128x128)
        int idx = (b-416)*256+tid;
        int r = idx >> 7, c = idx & 127;
        WT[c*128 + r] = (f16)giW[idx];
    } else if (b < 672){               // fwT = fw^T (384x128 -> 128x384)
        int idx = (b-480)*256+tid;
        int r = idx >> 7, c = idx & 127;
        fwT[c*384 + r] = (f16)fw[idx];
    } else if (b < 864){               // ggW16 = (f16)ggWih  [384][128]
        int idx = (b-672)*256+tid;
        ggW16[idx] = (f16)ggWih[idx];
    } else {                           // bucket
        if (tid < 16) cs[tid] = 0;
        __syncthreads();
        for (int s = tid; s < 2048; s += 256) atomicAdd(&cs[sec[s]], 1);
        __syncthreads();
        if (tid == 0){
            int acc = 0;
            for (int g=0; g<16; g++){ cnt[g]=cs[g]; base[g]=acc; wsc[g]=acc; acc+=cs[g]; }
        }
        __syncthreads();
        for (int s = tid; s < 2048; s += 256){
            int g = sec[s];
            int p = atomicAdd(&wsc[g], 1);
            memflat[p] = s;
        }
    }
}

// ---------------------------------------------------------------------------
// Short GRU+attn v3. M=16 seqs/block, 4096 blocks, 8 waves; wave w owns
// gate-col block w. Bx direct from global (A-side zero-pad covers k>=16).
// Lagged unnormalized softmax, 1 barrier/step. LDS ~9.5 KB.
// NOTE (512,2): (512,4) caps VGPR at 64 -> massive spill (R5). Keep >=128 cap.
// ---------------------------------------------------------------------------
__global__ __launch_bounds__(512,2) void gru_short(
    const float* __restrict__ x, const f16* __restrict__ Wcat,
    const float* __restrict__ bih, const float* __restrict__ bhh,
    const float* __restrict__ aw, const float* __restrict__ ab,
    f16* __restrict__ out)
{
    __shared__ __align__(16) f16 hs[2][16][136];
    __shared__ float scpart[2][8][16];
    const int tid = threadIdx.x, w = tid>>6, lane = tid&63;
    const int c = lane&15, quad = lane>>4;
    const int s0 = blockIdx.x*16;

    { f16x4 z4 = {0,0,0,0};
      f16x4* zh = (f16x4*)&hs[1][0][0];
      for (int i=tid; i<544; i+=512) zh[i] = z4; }

    auto loadBx = [&](int t)->f16x8 {
        f16x8 bx = {0,0,0,0,0,0,0,0};
        if (quad < 2){
            const float* px = &x[(size_t)(s0+c)*80 + t*16 + quad*8];
            float4 a = *(const float4*)px, bq = *(const float4*)(px+4);
            bx[0]=(f16)a.x; bx[1]=(f16)a.y; bx[2]=(f16)a.z; bx[3]=(f16)a.w;
            bx[4]=(f16)bq.x; bx[5]=(f16)bq.y; bx[6]=(f16)bq.z; bx[7]=(f16)bq.w;
        }
        return bx;
    };

    const int jrow = w*16 + c;
    f16x8 Ar[5], Az[5], Agi, Agh[4];
#pragma unroll
    for (int kb=0;kb<5;kb++){
        Ar[kb] = *(const f16x8*)&Wcat[(size_t)(jrow)*160 + kb*32 + quad*8];
        Az[kb] = *(const f16x8*)&Wcat[(size_t)(128+jrow)*160 + kb*32 + quad*8];
    }
    Agi = *(const f16x8*)&Wcat[(size_t)(256+jrow)*160 + quad*8];
#pragma unroll
    for (int i=0;i<4;i++)
        Agh[i] = *(const f16x8*)&Wcat[(size_t)(384+jrow)*160 + 32 + i*32 + quad*8];

    float brz_r[4], brz_z[4], b_in[4], b_hn[4], awr[4];
#pragma unroll
    for (int r=0;r<4;r++){
        int j = w*16 + quad*4 + r;
        brz_r[r] = bih[j] + bhh[j];
        brz_z[r] = bih[128+j] + bhh[128+j];
        b_in[r] = bih[256+j]; b_hn[r] = bhh[256+j];
        awr[r] = aw[j];
    }
    const float abv = ab[0];
    float hreg[4] = {0,0,0,0}, aacc[4] = {0,0,0,0}, l_ = 0.0f;
    f16x8 bxc = loadBx(0);
    __syncthreads();

#pragma unroll 1
    for (int t=0; t<5; ++t){
        const int rp = (t&1)^1, wp = t&1;
        f16x8 Bh[4];
#pragma unroll
        for (int i=0;i<4;i++)
            Bh[i] = *(const f16x8*)&hs[rp][c][i*32+quad*8];
        f16x8 bxn = {0,0,0,0,0,0,0,0};
        if (t < 4) bxn = loadBx(t+1);
        if (t > 0){
            float sc = abv;
#pragma unroll
            for (int ww=0; ww<8; ww++) sc += scpart[rp][ww][c];
            float e = __expf(sc);
            l_ += e;
#pragma unroll
            for (int r=0;r<4;r++) aacc[r] += e*hreg[r];
        }
        floatx4 ar = {0,0,0,0}, az = {0,0,0,0}, agi = {0,0,0,0}, agh = {0,0,0,0};
        ar = MFMA16(Ar[0], bxc, ar);
        az = MFMA16(Az[0], bxc, az);
        agi = MFMA16(Agi, bxc, agi);
#pragma unroll
        for (int i=0;i<4;i++){
            ar = MFMA16(Ar[1+i], Bh[i], ar);
            az = MFMA16(Az[1+i], Bh[i], az);
            agh = MFMA16(Agh[i], Bh[i], agh);
        }
        f16x4 h4;
        float sp = 0.0f;
#pragma unroll
        for (int r=0;r<4;r++){
            float rg = sigm_f(ar[r] + brz_r[r]);
            float zg = sigm_f(az[r] + brz_z[r]);
            float ng = tanh_f(agi[r] + b_in[r] + rg*(agh[r] + b_hn[r]));
            float hn = fmaf(zg, hreg[r] - ng, ng);
            hreg[r] = hn; h4[r] = (f16)hn;
            sp += hn * awr[r];
        }
        *(f16x4*)&hs[wp][c][w*16 + quad*4] = h4;
        sp += __shfl_xor(sp, 16);
        sp += __shfl_xor(sp, 32);
        if (lane < 16) scpart[wp][w][lane] = sp;
        bxc = bxn;
        __syncthreads();
    }
    // drain (t=4 wrote scpart[0] and hs[0])
    {
        float sc = abv;
#pragma unroll
        for (int ww=0; ww<8; ww++) sc += scpart[0][ww][c];
        float e = __expf(sc);
        l_ += e;
        float inv = rcpf(l_);
        f16x4 h4;
#pragma unroll
        for (int r=0;r<4;r++) h4[r] = (f16)((aacc[r] + e*hreg[r])*inv);
        *(f16x4*)&hs[0][c][w*16 + quad*4] = h4;
    }
    __syncthreads();
    if (tid < 256){
        int s = tid>>4, p = tid&15;
        *(f16x8*)&out[(size_t)(s0+s)*128 + p*8] = *(const f16x8*)&hs[0][s][p*8];
    }
}

// ---------------------------------------------------------------------------
// Merged: blocks 0..255 -> la GRU+attn (M=8 real); 256..319 -> gat_prep.
// ---------------------------------------------------------------------------
__global__ __launch_bounds__(512,2) void la_gatprep(
    const f16* __restrict__ shrt16, const f16* __restrict__ Wcat,
    const float* __restrict__ bih, const float* __restrict__ bhh,
    const float* __restrict__ aw, const float* __restrict__ ab,
    f16* __restrict__ la16,
    const f16* __restrict__ WT, const float* __restrict__ gia,
    const int* __restrict__ memflat,
    f16* __restrict__ Whs, float* __restrict__ ers, float* __restrict__ el)
{
    __shared__ __align__(16) char smem[17152];
    const int tid = threadIdx.x, w = tid>>6, lane = tid&63;
    const int c = lane&15, quad = lane>>4;

    if (blockIdx.x < 256){
        // ---------------- la GRU ----------------
        f16* hsp = (f16*)smem;                        // [2][16][136]
        float* scp = (float*)(smem + 2*16*136*2);     // [2][8][16]
        const int s0 = blockIdx.x*8;
        const int sx = (s0 + c < 2047) ? (s0 + c) : 2047;   // clamp phantom rows

        { f16x4 z4 = {0,0,0,0};
          f16x4* zh = (f16x4*)(hsp + 16*136);
          for (int i=tid; i<544; i+=512) zh[i] = z4; }

        const int jrow = w*16 + c;
        f16x8 Ar[8], Az[8], Agi[4], Agh[4];
#pragma unroll
        for (int kb=0;kb<8;kb++){
            Ar[kb] = *(const f16x8*)&Wcat[(size_t)(jrow)*256 + kb*32 + quad*8];
            Az[kb] = *(const f16x8*)&Wcat[(size_t)(128+jrow)*256 + kb*32 + quad*8];
        }
#pragma unroll
        for (int i=0;i<4;i++){
            Agi[i] = *(const f16x8*)&Wcat[(size_t)(256+jrow)*256 + i*32 + quad*8];
            Agh[i] = *(const f16x8*)&Wcat[(size_t)(384+jrow)*256 + 128 + i*32 + quad*8];
        }
        float brz_r[4], brz_z[4], b_in[4], b_hn[4], awr[4];
#pragma unroll
        for (int r=0;r<4;r++){
            int j = w*16 + quad*4 + r;
            brz_r[r] = bih[j] + bhh[j];
            brz_z[r] = bih[128+j] + bhh[128+j];
            b_in[r] = bih[256+j]; b_hn[r] = bhh[256+j];
            awr[r] = aw[j];
        }
        const float abv = ab[0];
        float hreg[4] = {0,0,0,0}, aacc[4] = {0,0,0,0}, l_ = 0.0f;
        f16x8 Bxc[4];
#pragma unroll
        for (int i=0;i<4;i++)
            Bxc[i] = *(const f16x8*)&shrt16[((size_t)sx*32 + 0)*128 + i*32 + quad*8];
        __syncthreads();

#pragma unroll 1
        for (int t=0; t<32; ++t){
            const int rp = (t&1)^1, wp = t&1;
            f16x8 Bh[4];
#pragma unroll
            for (int i=0;i<4;i++)
                Bh[i] = *(const f16x8*)&hsp[((size_t)rp*16 + c)*136 + i*32 + quad*8];
            f16x8 Bxn[4];
            if (t < 31){
#pragma unroll
                for (int i=0;i<4;i++)
                    Bxn[i] = *(const f16x8*)&shrt16[((size_t)sx*32 + t+1)*128 + i*32 + quad*8];
            }
            if (t > 0){
                float sc = abv;
#pragma unroll
                for (int ww=0; ww<8; ww++) sc += scp[(rp*8+ww)*16 + c];
                float e = __expf(sc);
                l_ += e;
#pragma unroll
                for (int r=0;r<4;r++) aacc[r] += e*hreg[r];
            }
            floatx4 ar = {0,0,0,0}, az = {0,0,0,0}, agi = {0,0,0,0}, agh = {0,0,0,0};
#pragma unroll
            for (int i=0;i<4;i++){
                ar = MFMA16(Ar[i], Bxc[i], ar);
                az = MFMA16(Az[i], Bxc[i], az);
                agi = MFMA16(Agi[i], Bxc[i], agi);
            }
#pragma unroll
            for (int i=0;i<4;i++){
                ar = MFMA16(Ar[4+i], Bh[i], ar);
                az = MFMA16(Az[4+i], Bh[i], az);
                agh = MFMA16(Agh[i], Bh[i], agh);
            }
            f16x4 h4;
            float sp = 0.0f;
#pragma unroll
            for (int r=0;r<4;r++){
                float rg = sigm_f(ar[r] + brz_r[r]);
                float zg = sigm_f(az[r] + brz_z[r]);
                float ng = tanh_f(agi[r] + b_in[r] + rg*(agh[r] + b_hn[r]));
                float hn = fmaf(zg, hreg[r] - ng, ng);
                hreg[r] = hn; h4[r] = (f16)hn;
                sp += hn * awr[r];
            }
            *(f16x4*)&hsp[((size_t)wp*16 + c)*136 + w*16 + quad*4] = h4;
            sp += __shfl_xor(sp, 16);
            sp += __shfl_xor(sp, 32);
            if (lane < 16) scp[(wp*8+w)*16 + lane] = sp;
#pragma unroll
            for (int i=0;i<4;i++) Bxc[i] = Bxn[i];
            __syncthreads();
        }
        // drain (t=31 wrote scp parity 1, hs parity 1)
        {
            float sc = abv;
#pragma unroll
            for (int ww=0; ww<8; ww++) sc += scp[(8+ww)*16 + c];
            float e = __expf(sc);
            l_ += e;
            float inv = rcpf(l_);
            f16x4 h4;
#pragma unroll
            for (int r=0;r<4;r++) h4[r] = (f16)((aacc[r] + e*hreg[r])*inv);
            *(f16x4*)&hsp[((size_t)16 + c)*136 + w*16 + quad*4] = h4;
        }
        __syncthreads();
        if (tid < 128){
            int s = tid>>4, p = tid&15;
            *(f16x8*)&la16[(size_t)(s0+s)*128 + p*8] =
                *(const f16x8*)&hsp[((size_t)16 + s)*136 + p*8];
        }
    } else {
        // ---------------- gat_prep (512-thread variant) ----------------
        float* tbuf = (float*)smem;                   // [32][132]
        int* rows = (int*)(smem + 32*132*4);
        const int p0 = (blockIdx.x - 256)*32;
        if (tid < 32) rows[tid] = memflat[p0 + tid];
        __syncthreads();
        f16x8 A[2][4];
#pragma unroll
        for (int mt=0;mt<2;mt++)
#pragma unroll
            for (int kb=0;kb<4;kb++)
                A[mt][kb] = *(const f16x8*)&shrt16[((size_t)rows[mt*16+c]*32 + 31)*128 + kb*32 + quad*8];
        const int jb = w;
        f16x8 B[4];
#pragma unroll
        for (int kb=0;kb<4;kb++)
            B[kb] = *(const f16x8*)&WT[(size_t)(jb*16+c)*128 + kb*32 + quad*8];
        floatx4 acc[2] = {{0,0,0,0},{0,0,0,0}};
#pragma unroll
        for (int kb=0;kb<4;kb++){
            acc[0] = MFMA16(A[0][kb], B[kb], acc[0]);
            acc[1] = MFMA16(A[1][kb], B[kb], acc[1]);
        }
#pragma unroll
        for (int mt=0;mt<2;mt++)
#pragma unroll
            for (int r=0;r<4;r++)
                tbuf[(mt*16 + quad*4 + r)*132 + jb*16 + c] = acc[mt][r];
        __syncthreads();
        for (int i=tid; i<1024; i+=512){
            int s = i>>5, p = i&31;
            float4 v = *(const float4*)&tbuf[s*132 + p*4];
            f16x4 h4; h4[0]=(f16)v.x; h4[1]=(f16)v.y; h4[2]=(f16)v.z; h4[3]=(f16)v.w;
            *(f16x4*)&Whs[(size_t)(p0+s)*128 + p*4] = h4;
        }
#pragma unroll
        for (int k=0; k<4; k++){
            int row = w*4 + k;
            float w0 = tbuf[row*132 + lane], w1 = tbuf[row*132 + 64 + lane];
            float v1 = w0*gia[lane]     + w1*gia[64+lane];
            float v2 = w0*gia[128+lane] + w1*gia[192+lane];
#pragma unroll
            for (int off=32; off; off>>=1){ v1 += __shfl_down(v1,off); v2 += __shfl_down(v2,off); }
            if (lane==0){ el[rows[row]] = v1; ers[p0+row] = v2; }
        }
    }
}

// ---------------------------------------------------------------------------
// GAT intra + fused T=1 lg GRU. One wave per row. Writes lg16 directly.
// ---------------------------------------------------------------------------
__global__ __launch_bounds__(256) void gat_intra_lg(
    const f16* __restrict__ Whs, const float* __restrict__ ers,
    const float* __restrict__ el, const int* __restrict__ sec,
    const int* __restrict__ cnt, const int* __restrict__ base,
    const f16* __restrict__ ggW16,
    const float* __restrict__ ggbih, const float* __restrict__ ggbhh,
    f16* __restrict__ lgout, int S)
{
    __shared__ __align__(16) f16 irow[4][136];
    int wave = threadIdx.x>>6, lane = threadIdx.x&63;
    int i = blockIdx.x*4 + wave;
    if (i>=S) return;
    int g = sec[i];
    int n = cnt[g], b = base[g];
    float eli = el[i];
    float m = -INFINITY;
    for (int jj=lane; jj<n; jj+=64){
        float v = eli + ers[b+jj]; v = v>0.f? v : LRELU_A*v;
        m = fmaxf(m, v);
    }
#pragma unroll
    for (int off=32; off; off>>=1) m = fmaxf(m, __shfl_xor(m, off));
    float l = 0.f, c0=0.f, c1=0.f;
#pragma unroll 4
    for (int jj=0; jj<n; jj++){
        float v = eli + ers[b+jj]; v = v>0.f? v : LRELU_A*v;
        float p = __expf(v-m);
        l += p;
        c0 += p*(float)Whs[(size_t)(b+jj)*128 + lane];
        c1 += p*(float)Whs[(size_t)(b+jj)*128 + 64 + lane];
    }
    float il = rcpf(l);
    c0 *= il; c1 *= il;
    float e0 = c0>0.f? c0 : expm1f(c0);
    float e1 = c1>0.f? c1 : expm1f(c1);
    irow[wave][lane] = (f16)e0;
    irow[wave][64+lane] = (f16)e1;
    // wave-private row: no block barrier needed (same wave reads its own row)
    float sr0=0,sr1=0,sz0=0,sz1=0,sn0=0,sn1=0;
    const int j0 = lane, j1 = 64 + lane;
#pragma unroll 4
    for (int kb=0; kb<16; kb++){
        f16x8 hv = *(const f16x8*)&irow[wave][kb*8];
        f16x8 wr0 = *(const f16x8*)&ggW16[(size_t)(j0)*128 + kb*8];
        f16x8 wr1 = *(const f16x8*)&ggW16[(size_t)(j1)*128 + kb*8];
        f16x8 wz0 = *(const f16x8*)&ggW16[(size_t)(128+j0)*128 + kb*8];
        f16x8 wz1 = *(const f16x8*)&ggW16[(size_t)(128+j1)*128 + kb*8];
        f16x8 wn0 = *(const f16x8*)&ggW16[(size_t)(256+j0)*128 + kb*8];
        f16x8 wn1 = *(const f16x8*)&ggW16[(size_t)(256+j1)*128 + kb*8];
#pragma unroll
        for (int e=0;e<8;e++){
            float h = (float)hv[e];
            sr0 = fmaf(h, (float)wr0[e], sr0);
            sr1 = fmaf(h, (float)wr1[e], sr1);
            sz0 = fmaf(h, (float)wz0[e], sz0);
            sz1 = fmaf(h, (float)wz1[e], sz1);
            sn0 = fmaf(h, (float)wn0[e], sn0);
            sn1 = fmaf(h, (float)wn1[e], sn1);
        }
    }
    float r0 = sigm_f(sr0 + ggbih[j0] + ggbhh[j0]);
    float r1 = sigm_f(sr1 + ggbih[j1] + ggbhh[j1]);
    float z0 = sigm_f(sz0 + ggbih[128+j0] + ggbhh[128+j0]);
    float z1 = sigm_f(sz1 + ggbih[128+j1] + ggbhh[128+j1]);
    float n0 = tanh_f(sn0 + ggbih[256+j0] + r0*ggbhh[256+j0]);
    float n1 = tanh_f(sn1 + ggbih[256+j1] + r1*ggbhh[256+j1]);
    lgout[(size_t)i*128 + j0] = (f16)((1.0f - z0)*n0);
    lgout[(size_t)i*128 + j1] = (f16)((1.0f - z1)*n1);
}

// ---------------------------------------------------------------------------
// sector means + 16-node inter GAT, one block of 512
// ---------------------------------------------------------------------------
__global__ __launch_bounds__(512) void mean_inter(
    const f16* __restrict__ lg16, const int* __restrict__ memflat,
    const int* __restrict__ cnt, const int* __restrict__ base,
    const int* __restrict__ adj, const float* __restrict__ W,
    const float* __restrict__ a, float* __restrict__ seco)
{
    __shared__ __align__(16) float hsf[16][132];
    __shared__ __align__(16) float Whq[16][132];
    __shared__ float elq[16], erq[16], att[16][16];
    const int tid = threadIdx.x;
    // phase 1: sector means
    for (int idx=tid; idx<2048; idx+=512){
        int g = idx>>7, j = idx&127;
        int n = cnt[g];
        const int* ml = memflat + base[g];
        float sum = 0.f;
        for (int k=0;k<n;k++) sum += (float)lg16[(size_t)ml[k]*128 + j];
        hsf[g][j] = sum * rcpf(fmaxf((float)n,1.0f));
    }
    __syncthreads();
    // phase 2: Wh
    for (int idx=tid; idx<2048; idx+=512){
        int o = idx&127, s = idx>>7;
        float a0=0.f,a1=0.f,a2=0.f,a3=0.f;
        for (int j=0;j<128;j+=4){
            a0 += hsf[s][j]  *W[(j  )*128+o];
            a1 += hsf[s][j+1]*W[(j+1)*128+o];
            a2 += hsf[s][j+2]*W[(j+2)*128+o];
            a3 += hsf[s][j+3]*W[(j+3)*128+o];
        }
        Whq[s][o]=(a0+a1)+(a2+a3);
    }
    __syncthreads();
    if (tid<32){
        int s=tid&15; int second = tid>>4;
        const float* av = a + (second?128:0);
        float acc=0.f; for(int o=0;o<128;o++) acc += Whq[s][o]*av[o];
        if (second) erq[s]=acc; else elq[s]=acc;
    }
    __syncthreads();
    if (tid<16){
        int i=tid; float m=NEGBIG; float e[16];
        for(int j=0;j<16;j++){
            float v = elq[i]+erq[j]; v = v>0.f? v : LRELU_A*v;
            e[j] = (adj[i*16+j]>0)? v : NEGBIG;
            m = fmaxf(m,e[j]);
        }
        float l=0.f;
        for(int j=0;j<16;j++){ float p=__expf(e[j]-m); att[i][j]=p; l+=p; }
        float il = rcpf(l);
        for(int j=0;j<16;j++) att[i][j] *= il;
    }
    __syncthreads();
    for (int idx=tid; idx<2048; idx+=512){
        int o = idx&127, s = idx>>7;
        float acc=0.f;
#pragma unroll
        for(int j=0;j<16;j++) acc += att[s][j]*Whq[j][o];
        seco[s*128+o] = acc>0.f? acc : expm1f(acc);
    }
}

// ---------------------------------------------------------------------------
// fused = [lg|la|sec_ps] @ fw + fb, then both heads in-kernel
// ---------------------------------------------------------------------------
__global__ __launch_bounds__(256) void fused_mfma(
    const f16* __restrict__ lg16, const f16* __restrict__ la16,
    const float* __restrict__ seco, const int* __restrict__ sec,
    const f16* __restrict__ fwT,
    const float* __restrict__ fb, const float* __restrict__ rw,
    const float* __restrict__ rb, const float* __restrict__ mw,
    const float* __restrict__ mb, float* __restrict__ outp)
{
    __shared__ float rpart[4][32], mpart[4][32];
    const int tid = threadIdx.x, w = tid>>6, lane = tid&63;
    const int c = lane&15, quad = lane>>4;
    const int s0 = blockIdx.x*32;
    f16x8 A[2][12];
#pragma unroll
    for (int mt=0;mt<2;mt++){
        int row = s0 + mt*16 + c;
        int g = sec[row];
#pragma unroll
        for (int kb=0;kb<4;kb++){
            A[mt][kb]   = *(const f16x8*)&lg16[(size_t)row*128 + kb*32 + quad*8];
            A[mt][4+kb] = *(const f16x8*)&la16[(size_t)row*128 + kb*32 + quad*8];
            A[mt][8+kb] = load_cvt8(&seco[(size_t)g*128 + kb*32 + quad*8]);
        }
    }
    float rsum[2][4] = {{0,0,0,0},{0,0,0,0}};
    float msum[2][4] = {{0,0,0,0},{0,0,0,0}};
#pragma unroll
    for (int i=0;i<2;i++){
        int jb = w*2 + i;
        int col = jb*16 + c;
        f16x8 B[12];
#pragma unroll
        for (int kb=0;kb<12;kb++)
            B[kb] = *(const f16x8*)&fwT[(size_t)col*384 + kb*32 + quad*8];
        floatx4 acc[2] = {{0,0,0,0},{0,0,0,0}};
#pragma unroll
        for (int kb=0;kb<12;kb++){
            acc[0] = MFMA16(A[0][kb], B[kb], acc[0]);
            acc[1] = MFMA16(A[1][kb], B[kb], acc[1]);
        }
        float fbv = fb[col], rwv = rw[col], mwv = mw[col];
#pragma unroll
        for (int mt=0;mt<2;mt++)
#pragma unroll
            for (int r=0;r<4;r++){
                float fu = acc[mt][r] + fbv;
                rsum[mt][r] += fu*rwv;
                msum[mt][r] += fu*mwv;
            }
    }
#pragma unroll
    for (int mt=0;mt<2;mt++)
#pragma unroll
        for (int r=0;r<4;r++){
#pragma unroll
            for (int off=1; off<16; off<<=1){
                rsum[mt][r] += __shfl_xor(rsum[mt][r], off);
                msum[mt][r] += __shfl_xor(msum[mt][r], off);
            }
            if (c==0){
                rpart[w][mt*16 + quad*4 + r] = rsum[mt][r];
                mpart[w][mt*16 + quad*4 + r] = msum[mt][r];
            }
        }
    __syncthreads();
    if (tid < 32){
        int s = tid;
        float rs = rb[0], ms = mb[0];
#pragma unroll
        for (int ww=0; ww<4; ww++){ rs += rpart[ww][s]; ms += mpart[ww][s]; }
        outp[s0+s] = rs;
        outp[2048 + s0 + s] = sigm(ms);
    }
}

extern "C" void kernel_launch(void* const* d_in, const int* in_sizes, int n_in,
                              void* d_out, int out_size, void* d_ws, size_t ws_size,
                              hipStream_t stream) {
    const float* sf    = (const float*)d_in[0];
    const int*   sec   = (const int*)  d_in[1];
    const int*   adj   = (const int*)  d_in[2];
    const float* g1Wih = (const float*)d_in[3];
    const float* g1Whh = (const float*)d_in[4];
    const float* g1bih = (const float*)d_in[5];
    const float* g1bhh = (const float*)d_in[6];
    const float* a1w   = (const float*)d_in[7];
    const float* a1b   = (const float*)d_in[8];
    const float* giW   = (const float*)d_in[9];
    const float* gia   = (const float*)d_in[10];
    const float* ggWih = (const float*)d_in[11];
    const float* ggbih = (const float*)d_in[13];
    const float* ggbhh = (const float*)d_in[14];
    const float* gaWih = (const float*)d_in[17];
    const float* gaWhh = (const float*)d_in[18];
    const float* gabih = (const float*)d_in[19];
    const float* gabhh = (const float*)d_in[20];
    const float* aaw   = (const float*)d_in[21];
    const float* aab   = (const float*)d_in[22];
    const float* geW   = (const float*)d_in[23];
    const float* gea   = (const float*)d_in[24];
    const float* fw    = (const float*)d_in[25];
    const float* fb    = (const float*)d_in[26];
    const float* rw    = (const float*)d_in[27];
    const float* rb    = (const float*)d_in[28];
    const float* mw    = (const float*)d_in[29];
    const float* mb    = (const float*)d_in[30];

    char* p = (char*)d_ws;
    f16*   shrt16 = (f16*)p;   p += (size_t)65536*128*2;
    f16*   lg16   = (f16*)p;   p += (size_t)262144*2;
    f16*   la16   = (f16*)p;   p += (size_t)262144*2;
    f16*   Whs    = (f16*)p;   p += (size_t)262144*2;
    f16*   Wcat1  = (f16*)p;   p += (size_t)512*160*2;
    f16*   WcatA  = (f16*)p;   p += (size_t)512*256*2;
    f16*   WT     = (f16*)p;   p += (size_t)16384*2;
    f16*   fwT    = (f16*)p;   p += (size_t)49152*2;
    f16*   ggW16  = (f16*)p;   p += (size_t)49152*2;
    float* el     = (float*)p; p += 2048*4;
    float* ers    = (float*)p; p += 2048*4;
    float* seco   = (float*)p; p += 2048*4;
    int*   memflat= (int*)p;   p += 2048*4;
    int*   cnt    = (int*)p;   p += 16*4;
    int*   basep  = (int*)p;   p += 16*4;

    // 0. weight prep + bucketing
    prep_kernel<<<865,256,0,stream>>>(g1Wih, g1Whh, gaWih, gaWhh, giW, fw, ggWih, sec,
                                      Wcat1, WcatA, WT, fwT, ggW16, memflat, cnt, basep);
    // 1. short GRU+attn (65536 windows, T=5), M=16/block
    gru_short<<<4096,512,0,stream>>>(sf, Wcat1, g1bih, g1bhh, a1w, a1b, shrt16);
    // 2. la GRU+attn (256 blocks) + gat_prep (64 blocks) merged
    la_gatprep<<<320,512,0,stream>>>(shrt16, WcatA, gabih, gabhh, aaw, aab, la16,
                                     WT, gia, memflat, Whs, ers, el);
    // 3. intra-sector GAT + lg (T=1 GRU) fused
    gat_intra_lg<<<512,256,0,stream>>>(Whs, ers, el, sec, cnt, basep,
                                       ggW16, ggbih, ggbhh, lg16, 2048);
    // 4. sector means + inter-sector GAT
    mean_inter<<<1,512,0,stream>>>(lg16, memflat, cnt, basep, adj, geW, gea, seco);
    // 5. fusion + heads
    fused_mfma<<<64,256,0,stream>>>(lg16, la16, seco, sec, fwT, fb, rw, rb, mw, mb, (float*)d_out);
}

// Round 8
// 449.710 us; speedup vs baseline: 1.4591x; 1.4591x over previous
//
#include <hip/hip_runtime.h>
#include <math.h>

#define LRELU_A 0.2f
#define NEGBIG (-9.0e15f)

typedef _Float16 f16;
typedef _Float16 f16x8 __attribute__((ext_vector_type(8)));
typedef _Float16 f16x4 __attribute__((ext_vector_type(4)));
typedef float floatx4 __attribute__((ext_vector_type(4)));

__device__ __forceinline__ float rcpf(float x){ return __builtin_amdgcn_rcpf(x); }
__device__ __forceinline__ float sigm_f(float x){ return rcpf(1.0f + __expf(-x)); }
__device__ __forceinline__ float tanh_f(float x){ return 1.0f - 2.0f*rcpf(1.0f + __expf(2.0f*x)); }
__device__ __forceinline__ float sigm(float x){ return rcpf(1.0f+__expf(-x)); }
__device__ __forceinline__ f16x8 load_cvt8(const float* __restrict__ p){
    float4 a = *(const float4*)p; float4 b = *(const float4*)(p+4);
    f16x8 r; r[0]=(f16)a.x; r[1]=(f16)a.y; r[2]=(f16)a.z; r[3]=(f16)a.w;
    r[4]=(f16)b.x; r[5]=(f16)b.y; r[6]=(f16)b.z; r[7]=(f16)b.w;
    return r;
}
#define MFMA16(A,B,C) __builtin_amdgcn_mfma_f32_16x16x32_f16((A),(B),(C),0,0,0)

// ---------------------------------------------------------------------------
// prep: Wcat1 | WcatA | WT | fwT | ggW16 | bucket. 865 blocks.
// ---------------------------------------------------------------------------
__global__ __launch_bounds__(256) void prep_kernel(
    const float* __restrict__ g1Wih, const float* __restrict__ g1Whh,
    const float* __restrict__ gaWih, const float* __restrict__ gaWhh,
    const float* __restrict__ giW,   const float* __restrict__ fw,
    const float* __restrict__ ggWih, const int* __restrict__ sec,
    f16* __restrict__ Wcat1, f16* __restrict__ WcatA,
    f16* __restrict__ WT, f16* __restrict__ fwT, f16* __restrict__ ggW16,
    int* __restrict__ memflat, int* __restrict__ cnt, int* __restrict__ base)
{
    __shared__ int cs[16], wsc[16];
    const int b = blockIdx.x, tid = threadIdx.x;
    if (b < 160){                      // Wcat1: INF=16, INFPAD=32, KTOT=160
        for (int idx = b*256+tid; idx < 512*160; idx += 160*256){
            int r = idx/160, k = idx - r*160;
            float v = 0.0f;
            if (r < 256){ if (k < 32){ if (k < 16) v = g1Wih[r*16+k]; } else v = g1Whh[r*128 + (k-32)]; }
            else if (r < 384){ if (k < 16) v = g1Wih[r*16+k]; }
            else { if (k >= 32) v = g1Whh[(r-128)*128 + (k-32)]; }
            Wcat1[idx] = (f16)v;
        }
    } else if (b < 416){               // WcatA: INF=128, KTOT=256
        for (int idx = (b-160)*256+tid; idx < 512*256; idx += 256*256){
            int r = idx >> 8, k = idx & 255;
            float v = 0.0f;
            if (r < 256){ v = (k < 128) ? gaWih[r*128+k] : gaWhh[r*128 + (k-128)]; }
            else if (r < 384){ if (k < 128) v = gaWih[r*128+k]; }
            else { if (k >= 128) v = gaWhh[(r-128)*128 + (k-128)]; }
            WcatA[idx] = (f16)v;
        }
    } else if (b < 480){               // WT = giW^T (128x128)
        int idx = (b-416)*256+tid;
        int r = idx >> 7, c = idx & 127;
        WT[c*128 + r] = (f16)giW[idx];
    } else if (b < 672){               // fwT = fw^T (384x128 -> 128x384)
        int idx = (b-480)*256+tid;
        int r = idx >> 7, c = idx & 127;
        fwT[c*384 + r] = (f16)fw[idx];
    } else if (b < 864){               // ggW16 = (f16)ggWih  [384][128]
        int idx = (b-672)*256+tid;
        ggW16[idx] = (f16)ggWih[idx];
    } else {                           // bucket
        if (tid < 16) cs[tid] = 0;
        __syncthreads();
        for (int s = tid; s < 2048; s += 256) atomicAdd(&cs[sec[s]], 1);
        __syncthreads();
        if (tid == 0){
            int acc = 0;
            for (int g=0; g<16; g++){ cnt[g]=cs[g]; base[g]=acc; wsc[g]=acc; acc+=cs[g]; }
        }
        __syncthreads();
        for (int s = tid; s < 2048; s += 256){
            int g = sec[s];
            int p = atomicAdd(&wsc[g], 1);
            memflat[p] = s;
        }
    }
}

// ---------------------------------------------------------------------------
// Short GRU+attn v3. M=16 seqs/block, 4096 blocks, 8 waves.
// NOTE (512,2): (512,4) caps VGPR at 64 -> massive spill (R5).
// ---------------------------------------------------------------------------
__global__ __launch_bounds__(512,2) void gru_short(
    const float* __restrict__ x, const f16* __restrict__ Wcat,
    const float* __restrict__ bih, const float* __restrict__ bhh,
    const float* __restrict__ aw, const float* __restrict__ ab,
    f16* __restrict__ out)
{
    __shared__ __align__(16) f16 hs[2][16][136];
    __shared__ float scpart[2][8][16];
    const int tid = threadIdx.x, w = tid>>6, lane = tid&63;
    const int c = lane&15, quad = lane>>4;
    const int s0 = blockIdx.x*16;

    { f16x4 z4 = {0,0,0,0};
      f16x4* zh = (f16x4*)&hs[1][0][0];
      for (int i=tid; i<544; i+=512) zh[i] = z4; }

    auto loadBx = [&](int t)->f16x8 {
        f16x8 bx = {0,0,0,0,0,0,0,0};
        if (quad < 2){
            const float* px = &x[(size_t)(s0+c)*80 + t*16 + quad*8];
            float4 a = *(const float4*)px, bq = *(const float4*)(px+4);
            bx[0]=(f16)a.x; bx[1]=(f16)a.y; bx[2]=(f16)a.z; bx[3]=(f16)a.w;
            bx[4]=(f16)bq.x; bx[5]=(f16)bq.y; bx[6]=(f16)bq.z; bx[7]=(f16)bq.w;
        }
        return bx;
    };

    const int jrow = w*16 + c;
    f16x8 Ar[5], Az[5], Agi, Agh[4];
#pragma unroll
    for (int kb=0;kb<5;kb++){
        Ar[kb] = *(const f16x8*)&Wcat[(size_t)(jrow)*160 + kb*32 + quad*8];
        Az[kb] = *(const f16x8*)&Wcat[(size_t)(128+jrow)*160 + kb*32 + quad*8];
    }
    Agi = *(const f16x8*)&Wcat[(size_t)(256+jrow)*160 + quad*8];
#pragma unroll
    for (int i=0;i<4;i++)
        Agh[i] = *(const f16x8*)&Wcat[(size_t)(384+jrow)*160 + 32 + i*32 + quad*8];

    float brz_r[4], brz_z[4], b_in[4], b_hn[4], awr[4];
#pragma unroll
    for (int r=0;r<4;r++){
        int j = w*16 + quad*4 + r;
        brz_r[r] = bih[j] + bhh[j];
        brz_z[r] = bih[128+j] + bhh[128+j];
        b_in[r] = bih[256+j]; b_hn[r] = bhh[256+j];
        awr[r] = aw[j];
    }
    const float abv = ab[0];
    float hreg[4] = {0,0,0,0}, aacc[4] = {0,0,0,0}, l_ = 0.0f;
    f16x8 bxc = loadBx(0);
    __syncthreads();

#pragma unroll 1
    for (int t=0; t<5; ++t){
        const int rp = (t&1)^1, wp = t&1;
        f16x8 Bh[4];
#pragma unroll
        for (int i=0;i<4;i++)
            Bh[i] = *(const f16x8*)&hs[rp][c][i*32+quad*8];
        f16x8 bxn = {0,0,0,0,0,0,0,0};
        if (t < 4) bxn = loadBx(t+1);
        if (t > 0){
            float sc = abv;
#pragma unroll
            for (int ww=0; ww<8; ww++) sc += scpart[rp][ww][c];
            float e = __expf(sc);
            l_ += e;
#pragma unroll
            for (int r=0;r<4;r++) aacc[r] += e*hreg[r];
        }
        floatx4 ar = {0,0,0,0}, az = {0,0,0,0}, agi = {0,0,0,0}, agh = {0,0,0,0};
        ar = MFMA16(Ar[0], bxc, ar);
        az = MFMA16(Az[0], bxc, az);
        agi = MFMA16(Agi, bxc, agi);
#pragma unroll
        for (int i=0;i<4;i++){
            ar = MFMA16(Ar[1+i], Bh[i], ar);
            az = MFMA16(Az[1+i], Bh[i], az);
            agh = MFMA16(Agh[i], Bh[i], agh);
        }
        f16x4 h4;
        float sp = 0.0f;
#pragma unroll
        for (int r=0;r<4;r++){
            float rg = sigm_f(ar[r] + brz_r[r]);
            float zg = sigm_f(az[r] + brz_z[r]);
            float ng = tanh_f(agi[r] + b_in[r] + rg*(agh[r] + b_hn[r]));
            float hn = fmaf(zg, hreg[r] - ng, ng);
            hreg[r] = hn; h4[r] = (f16)hn;
            sp += hn * awr[r];
        }
        *(f16x4*)&hs[wp][c][w*16 + quad*4] = h4;
        sp += __shfl_xor(sp, 16);
        sp += __shfl_xor(sp, 32);
        if (lane < 16) scpart[wp][w][lane] = sp;
        bxc = bxn;
        __syncthreads();
    }
    // drain (t=4 wrote scpart[0] and hs[0])
    {
        float sc = abv;
#pragma unroll
        for (int ww=0; ww<8; ww++) sc += scpart[0][ww][c];
        float e = __expf(sc);
        l_ += e;
        float inv = rcpf(l_);
        f16x4 h4;
#pragma unroll
        for (int r=0;r<4;r++) h4[r] = (f16)((aacc[r] + e*hreg[r])*inv);
        *(f16x4*)&hs[0][c][w*16 + quad*4] = h4;
    }
    __syncthreads();
    if (tid < 256){
        int s = tid>>4, p = tid&15;
        *(f16x8*)&out[(size_t)(s0+s)*128 + p*8] = *(const f16x8*)&hs[0][s][p*8];
    }
}

// ---------------------------------------------------------------------------
// Merged: blocks 0..255 -> la GRU+attn (M=8 real); 256..319 -> gat_prep.
// ---------------------------------------------------------------------------
__global__ __launch_bounds__(512,2) void la_gatprep(
    const f16* __restrict__ shrt16, const f16* __restrict__ Wcat,
    const float* __restrict__ bih, const float* __restrict__ bhh,
    const float* __restrict__ aw, const float* __restrict__ ab,
    f16* __restrict__ la16,
    const f16* __restrict__ WT, const float* __restrict__ gia,
    const int* __restrict__ memflat,
    f16* __restrict__ Whs, float* __restrict__ ers, float* __restrict__ el)
{
    __shared__ __align__(16) char smem[17152];
    const int tid = threadIdx.x, w = tid>>6, lane = tid&63;
    const int c = lane&15, quad = lane>>4;

    if (blockIdx.x < 256){
        // ---------------- la GRU ----------------
        f16* hsp = (f16*)smem;                        // [2][16][136]
        float* scp = (float*)(smem + 2*16*136*2);     // [2][8][16]
        const int s0 = blockIdx.x*8;
        const int sx = (s0 + c < 2047) ? (s0 + c) : 2047;

        { f16x4 z4 = {0,0,0,0};
          f16x4* zh = (f16x4*)(hsp + 16*136);
          for (int i=tid; i<544; i+=512) zh[i] = z4; }

        const int jrow = w*16 + c;
        f16x8 Ar[8], Az[8], Agi[4], Agh[4];
#pragma unroll
        for (int kb=0;kb<8;kb++){
            Ar[kb] = *(const f16x8*)&Wcat[(size_t)(jrow)*256 + kb*32 + quad*8];
            Az[kb] = *(const f16x8*)&Wcat[(size_t)(128+jrow)*256 + kb*32 + quad*8];
        }
#pragma unroll
        for (int i=0;i<4;i++){
            Agi[i] = *(const f16x8*)&Wcat[(size_t)(256+jrow)*256 + i*32 + quad*8];
            Agh[i] = *(const f16x8*)&Wcat[(size_t)(384+jrow)*256 + 128 + i*32 + quad*8];
        }
        float brz_r[4], brz_z[4], b_in[4], b_hn[4], awr[4];
#pragma unroll
        for (int r=0;r<4;r++){
            int j = w*16 + quad*4 + r;
            brz_r[r] = bih[j] + bhh[j];
            brz_z[r] = bih[128+j] + bhh[128+j];
            b_in[r] = bih[256+j]; b_hn[r] = bhh[256+j];
            awr[r] = aw[j];
        }
        const float abv = ab[0];
        float hreg[4] = {0,0,0,0}, aacc[4] = {0,0,0,0}, l_ = 0.0f;
        f16x8 Bxc[4];
#pragma unroll
        for (int i=0;i<4;i++)
            Bxc[i] = *(const f16x8*)&shrt16[((size_t)sx*32 + 0)*128 + i*32 + quad*8];
        __syncthreads();

#pragma unroll 1
        for (int t=0; t<32; ++t){
            const int rp = (t&1)^1, wp = t&1;
            f16x8 Bh[4];
#pragma unroll
            for (int i=0;i<4;i++)
                Bh[i] = *(const f16x8*)&hsp[((size_t)rp*16 + c)*136 + i*32 + quad*8];
            f16x8 Bxn[4];
            if (t < 31){
#pragma unroll
                for (int i=0;i<4;i++)
                    Bxn[i] = *(const f16x8*)&shrt16[((size_t)sx*32 + t+1)*128 + i*32 + quad*8];
            }
            if (t > 0){
                float sc = abv;
#pragma unroll
                for (int ww=0; ww<8; ww++) sc += scp[(rp*8+ww)*16 + c];
                float e = __expf(sc);
                l_ += e;
#pragma unroll
                for (int r=0;r<4;r++) aacc[r] += e*hreg[r];
            }
            floatx4 ar = {0,0,0,0}, az = {0,0,0,0}, agi = {0,0,0,0}, agh = {0,0,0,0};
#pragma unroll
            for (int i=0;i<4;i++){
                ar = MFMA16(Ar[i], Bxc[i], ar);
                az = MFMA16(Az[i], Bxc[i], az);
                agi = MFMA16(Agi[i], Bxc[i], agi);
            }
#pragma unroll
            for (int i=0;i<4;i++){
                ar = MFMA16(Ar[4+i], Bh[i], ar);
                az = MFMA16(Az[4+i], Bh[i], az);
                agh = MFMA16(Agh[i], Bh[i], agh);
            }
            f16x4 h4;
            float sp = 0.0f;
#pragma unroll
            for (int r=0;r<4;r++){
                float rg = sigm_f(ar[r] + brz_r[r]);
                float zg = sigm_f(az[r] + brz_z[r]);
                float ng = tanh_f(agi[r] + b_in[r] + rg*(agh[r] + b_hn[r]));
                float hn = fmaf(zg, hreg[r] - ng, ng);
                hreg[r] = hn; h4[r] = (f16)hn;
                sp += hn * awr[r];
            }
            *(f16x4*)&hsp[((size_t)wp*16 + c)*136 + w*16 + quad*4] = h4;
            sp += __shfl_xor(sp, 16);
            sp += __shfl_xor(sp, 32);
            if (lane < 16) scp[(wp*8+w)*16 + lane] = sp;
#pragma unroll
            for (int i=0;i<4;i++) Bxc[i] = Bxn[i];
            __syncthreads();
        }
        // drain (t=31 wrote parity 1)
        {
            float sc = abv;
#pragma unroll
            for (int ww=0; ww<8; ww++) sc += scp[(8+ww)*16 + c];
            float e = __expf(sc);
            l_ += e;
            float inv = rcpf(l_);
            f16x4 h4;
#pragma unroll
            for (int r=0;r<4;r++) h4[r] = (f16)((aacc[r] + e*hreg[r])*inv);
            *(f16x4*)&hsp[((size_t)16 + c)*136 + w*16 + quad*4] = h4;
        }
        __syncthreads();
        if (tid < 128){
            int s = tid>>4, p = tid&15;
            *(f16x8*)&la16[(size_t)(s0+s)*128 + p*8] =
                *(const f16x8*)&hsp[((size_t)16 + s)*136 + p*8];
        }
    } else {
        // ---------------- gat_prep (512-thread variant) ----------------
        float* tbuf = (float*)smem;                   // [32][132]
        int* rows = (int*)(smem + 32*132*4);
        const int p0 = (blockIdx.x - 256)*32;
        if (tid < 32) rows[tid] = memflat[p0 + tid];
        __syncthreads();
        f16x8 A[2][4];
#pragma unroll
        for (int mt=0;mt<2;mt++)
#pragma unroll
            for (int kb=0;kb<4;kb++)
                A[mt][kb] = *(const f16x8*)&shrt16[((size_t)rows[mt*16+c]*32 + 31)*128 + kb*32 + quad*8];
        const int jb = w;
        f16x8 B[4];
#pragma unroll
        for (int kb=0;kb<4;kb++)
            B[kb] = *(const f16x8*)&WT[(size_t)(jb*16+c)*128 + kb*32 + quad*8];
        floatx4 acc[2] = {{0,0,0,0},{0,0,0,0}};
#pragma unroll
        for (int kb=0;kb<4;kb++){
            acc[0] = MFMA16(A[0][kb], B[kb], acc[0]);
            acc[1] = MFMA16(A[1][kb], B[kb], acc[1]);
        }
#pragma unroll
        for (int mt=0;mt<2;mt++)
#pragma unroll
            for (int r=0;r<4;r++)
                tbuf[(mt*16 + quad*4 + r)*132 + jb*16 + c] = acc[mt][r];
        __syncthreads();
        for (int i=tid; i<1024; i+=512){
            int s = i>>5, p = i&31;
            float4 v = *(const float4*)&tbuf[s*132 + p*4];
            f16x4 h4; h4[0]=(f16)v.x; h4[1]=(f16)v.y; h4[2]=(f16)v.z; h4[3]=(f16)v.w;
            *(f16x4*)&Whs[(size_t)(p0+s)*128 + p*4] = h4;
        }
#pragma unroll
        for (int k=0; k<4; k++){
            int row = w*4 + k;
            float w0 = tbuf[row*132 + lane], w1 = tbuf[row*132 + 64 + lane];
            float v1 = w0*gia[lane]     + w1*gia[64+lane];
            float v2 = w0*gia[128+lane] + w1*gia[192+lane];
#pragma unroll
            for (int off=32; off; off>>=1){ v1 += __shfl_down(v1,off); v2 += __shfl_down(v2,off); }
            if (lane==0){ el[rows[row]] = v1; ers[p0+row] = v2; }
        }
    }
}

// ---------------------------------------------------------------------------
// GAT intra + fused T=1 lg GRU. One wave per SORTED row p.
// Writes lg16 (orig order, for fusion) and lgs (sorted, for sector means).
// ---------------------------------------------------------------------------
__global__ __launch_bounds__(256) void gat_intra_lg(
    const f16* __restrict__ Whs, const float* __restrict__ ers,
    const float* __restrict__ el, const int* __restrict__ sec,
    const int* __restrict__ cnt, const int* __restrict__ base,
    const int* __restrict__ memflat,
    const f16* __restrict__ ggW16,
    const float* __restrict__ ggbih, const float* __restrict__ ggbhh,
    f16* __restrict__ lgout, f16* __restrict__ lgs, int S)
{
    __shared__ __align__(16) f16 irow[4][136];
    int wave = threadIdx.x>>6, lane = threadIdx.x&63;
    int p = blockIdx.x*4 + wave;
    if (p>=S) return;
    int i = memflat[p];
    int g = sec[i];
    int n = cnt[g], b = base[g];
    float eli = el[i];
    float m = -INFINITY;
    for (int jj=lane; jj<n; jj+=64){
        float v = eli + ers[b+jj]; v = v>0.f? v : LRELU_A*v;
        m = fmaxf(m, v);
    }
#pragma unroll
    for (int off=32; off; off>>=1) m = fmaxf(m, __shfl_xor(m, off));
    float l = 0.f, c0=0.f, c1=0.f;
#pragma unroll 4
    for (int jj=0; jj<n; jj++){
        float v = eli + ers[b+jj]; v = v>0.f? v : LRELU_A*v;
        float pw = __expf(v-m);
        l += pw;
        c0 += pw*(float)Whs[(size_t)(b+jj)*128 + lane];
        c1 += pw*(float)Whs[(size_t)(b+jj)*128 + 64 + lane];
    }
    float il = rcpf(l);
    c0 *= il; c1 *= il;
    float e0 = c0>0.f? c0 : expm1f(c0);
    float e1 = c1>0.f? c1 : expm1f(c1);
    irow[wave][lane] = (f16)e0;
    irow[wave][64+lane] = (f16)e1;
    // wave-private row: no block barrier needed
    float sr0=0,sr1=0,sz0=0,sz1=0,sn0=0,sn1=0;
    const int j0 = lane, j1 = 64 + lane;
#pragma unroll 4
    for (int kb=0; kb<16; kb++){
        f16x8 hv = *(const f16x8*)&irow[wave][kb*8];
        f16x8 wr0 = *(const f16x8*)&ggW16[(size_t)(j0)*128 + kb*8];
        f16x8 wr1 = *(const f16x8*)&ggW16[(size_t)(j1)*128 + kb*8];
        f16x8 wz0 = *(const f16x8*)&ggW16[(size_t)(128+j0)*128 + kb*8];
        f16x8 wz1 = *(const f16x8*)&ggW16[(size_t)(128+j1)*128 + kb*8];
        f16x8 wn0 = *(const f16x8*)&ggW16[(size_t)(256+j0)*128 + kb*8];
        f16x8 wn1 = *(const f16x8*)&ggW16[(size_t)(256+j1)*128 + kb*8];
#pragma unroll
        for (int e=0;e<8;e++){
            float h = (float)hv[e];
            sr0 = fmaf(h, (float)wr0[e], sr0);
            sr1 = fmaf(h, (float)wr1[e], sr1);
            sz0 = fmaf(h, (float)wz0[e], sz0);
            sz1 = fmaf(h, (float)wz1[e], sz1);
            sn0 = fmaf(h, (float)wn0[e], sn0);
            sn1 = fmaf(h, (float)wn1[e], sn1);
        }
    }
    float r0 = sigm_f(sr0 + ggbih[j0] + ggbhh[j0]);
    float r1 = sigm_f(sr1 + ggbih[j1] + ggbhh[j1]);
    float z0 = sigm_f(sz0 + ggbih[128+j0] + ggbhh[128+j0]);
    float z1 = sigm_f(sz1 + ggbih[128+j1] + ggbhh[128+j1]);
    float n0 = tanh_f(sn0 + ggbih[256+j0] + r0*ggbhh[256+j0]);
    float n1 = tanh_f(sn1 + ggbih[256+j1] + r1*ggbhh[256+j1]);
    f16 v0 = (f16)((1.0f - z0)*n0);
    f16 v1 = (f16)((1.0f - z1)*n1);
    lgout[(size_t)i*128 + j0] = v0;
    lgout[(size_t)i*128 + j1] = v1;
    lgs[(size_t)p*128 + j0] = v0;
    lgs[(size_t)p*128 + j1] = v1;
}

// sector means over SORTED lgs: block g, thread j, contiguous stream
__global__ __launch_bounds__(128) void sector_mean_sorted(
    const f16* __restrict__ lgs, const int* __restrict__ cnt,
    const int* __restrict__ base, float* __restrict__ secf)
{
    int g = blockIdx.x, j = threadIdx.x;
    int n = cnt[g], b = base[g];
    float sum=0.f;
    for (int k=0;k<n;k++) sum += (float)lgs[(size_t)(b+k)*128 + j];
    secf[g*128+j] = sum * rcpf(fmaxf((float)n,1.0f));
}

__global__ __launch_bounds__(256) void gat_inter_kernel(
    const float* __restrict__ secf, const int* __restrict__ adj,
    const float* __restrict__ W, const float* __restrict__ a,
    float* __restrict__ outp)
{
    __shared__ __align__(16) float hsf[16][132];
    __shared__ __align__(16) float Whq[16][132];
    __shared__ float elq[16], erq[16], att[16][16];
    const int tid=threadIdx.x;
    for (int idx=tid; idx<2048; idx+=256){ int s=idx>>7,j=idx&127; hsf[s][j]=secf[idx]; }
    __syncthreads();
#pragma unroll 1
    for (int i=0;i<8;i++){
        int idx=i*256+tid; int o=idx&127, s=idx>>7;
        float a0=0.f,a1=0.f,a2=0.f,a3=0.f;
        for (int j=0;j<128;j+=4){
            a0 += hsf[s][j]  *W[(j  )*128+o];
            a1 += hsf[s][j+1]*W[(j+1)*128+o];
            a2 += hsf[s][j+2]*W[(j+2)*128+o];
            a3 += hsf[s][j+3]*W[(j+3)*128+o];
        }
        Whq[s][o]=(a0+a1)+(a2+a3);
    }
    __syncthreads();
    if (tid<32){
        int s=tid&15; int second = tid>>4;
        const float* av = a + (second?128:0);
        float acc=0.f; for(int o=0;o<128;o++) acc += Whq[s][o]*av[o];
        if (second) erq[s]=acc; else elq[s]=acc;
    }
    __syncthreads();
    if (tid<16){
        int i=tid; float m=NEGBIG; float e[16];
        for(int j=0;j<16;j++){
            float v = elq[i]+erq[j]; v = v>0.f? v : LRELU_A*v;
            e[j] = (adj[i*16+j]>0)? v : NEGBIG;
            m = fmaxf(m,e[j]);
        }
        float l=0.f;
        for(int j=0;j<16;j++){ float p=__expf(e[j]-m); att[i][j]=p; l+=p; }
        float il = rcpf(l);
        for(int j=0;j<16;j++) att[i][j] *= il;
    }
    __syncthreads();
#pragma unroll
    for (int i=0;i<8;i++){
        int idx=i*256+tid; int o=idx&127, s=idx>>7;
        float acc=0.f;
#pragma unroll
        for(int j=0;j<16;j++) acc += att[s][j]*Whq[j][o];
        outp[s*128+o] = acc>0.f? acc : expm1f(acc);
    }
}

// ---------------------------------------------------------------------------
// fused = [lg|la|sec_ps] @ fw + fb, then both heads in-kernel
// ---------------------------------------------------------------------------
__global__ __launch_bounds__(256) void fused_mfma(
    const f16* __restrict__ lg16, const f16* __restrict__ la16,
    const float* __restrict__ seco, const int* __restrict__ sec,
    const f16* __restrict__ fwT,
    const float* __restrict__ fb, const float* __restrict__ rw,
    const float* __restrict__ rb, const float* __restrict__ mw,
    const float* __restrict__ mb, float* __restrict__ outp)
{
    __shared__ float rpart[4][32], mpart[4][32];
    const int tid = threadIdx.x, w = tid>>6, lane = tid&63;
    const int c = lane&15, quad = lane>>4;
    const int s0 = blockIdx.x*32;
    f16x8 A[2][12];
#pragma unroll
    for (int mt=0;mt<2;mt++){
        int row = s0 + mt*16 + c;
        int g = sec[row];
#pragma unroll
        for (int kb=0;kb<4;kb++){
            A[mt][kb]   = *(const f16x8*)&lg16[(size_t)row*128 + kb*32 + quad*8];
            A[mt][4+kb] = *(const f16x8*)&la16[(size_t)row*128 + kb*32 + quad*8];
            A[mt][8+kb] = load_cvt8(&seco[(size_t)g*128 + kb*32 + quad*8]);
        }
    }
    float rsum[2][4] = {{0,0,0,0},{0,0,0,0}};
    float msum[2][4] = {{0,0,0,0},{0,0,0,0}};
#pragma unroll
    for (int i=0;i<2;i++){
        int jb = w*2 + i;
        int col = jb*16 + c;
        f16x8 B[12];
#pragma unroll
        for (int kb=0;kb<12;kb++)
            B[kb] = *(const f16x8*)&fwT[(size_t)col*384 + kb*32 + quad*8];
        floatx4 acc[2] = {{0,0,0,0},{0,0,0,0}};
#pragma unroll
        for (int kb=0;kb<12;kb++){
            acc[0] = MFMA16(A[0][kb], B[kb], acc[0]);
            acc[1] = MFMA16(A[1][kb], B[kb], acc[1]);
        }
        float fbv = fb[col], rwv = rw[col], mwv = mw[col];
#pragma unroll
        for (int mt=0;mt<2;mt++)
#pragma unroll
            for (int r=0;r<4;r++){
                float fu = acc[mt][r] + fbv;
                rsum[mt][r] += fu*rwv;
                msum[mt][r] += fu*mwv;
            }
    }
#pragma unroll
    for (int mt=0;mt<2;mt++)
#pragma unroll
        for (int r=0;r<4;r++){
#pragma unroll
            for (int off=1; off<16; off<<=1){
                rsum[mt][r] += __shfl_xor(rsum[mt][r], off);
                msum[mt][r] += __shfl_xor(msum[mt][r], off);
            }
            if (c==0){
                rpart[w][mt*16 + quad*4 + r] = rsum[mt][r];
                mpart[w][mt*16 + quad*4 + r] = msum[mt][r];
            }
        }
    __syncthreads();
    if (tid < 32){
        int s = tid;
        float rs = rb[0], ms = mb[0];
#pragma unroll
        for (int ww=0; ww<4; ww++){ rs += rpart[ww][s]; ms += mpart[ww][s]; }
        outp[s0+s] = rs;
        outp[2048 + s0 + s] = sigm(ms);
    }
}

extern "C" void kernel_launch(void* const* d_in, const int* in_sizes, int n_in,
                              void* d_out, int out_size, void* d_ws, size_t ws_size,
                              hipStream_t stream) {
    const float* sf    = (const float*)d_in[0];
    const int*   sec   = (const int*)  d_in[1];
    const int*   adj   = (const int*)  d_in[2];
    const float* g1Wih = (const float*)d_in[3];
    const float* g1Whh = (const float*)d_in[4];
    const float* g1bih = (const float*)d_in[5];
    const float* g1bhh = (const float*)d_in[6];
    const float* a1w   = (const float*)d_in[7];
    const float* a1b   = (const float*)d_in[8];
    const float* giW   = (const float*)d_in[9];
    const float* gia   = (const float*)d_in[10];
    const float* ggWih = (const float*)d_in[11];
    const float* ggbih = (const float*)d_in[13];
    const float* ggbhh = (const float*)d_in[14];
    const float* gaWih = (const float*)d_in[17];
    const float* gaWhh = (const float*)d_in[18];
    const float* gabih = (const float*)d_in[19];
    const float* gabhh = (const float*)d_in[20];
    const float* aaw   = (const float*)d_in[21];
    const float* aab   = (const float*)d_in[22];
    const float* geW   = (const float*)d_in[23];
    const float* gea   = (const float*)d_in[24];
    const float* fw    = (const float*)d_in[25];
    const float* fb    = (const float*)d_in[26];
    const float* rw    = (const float*)d_in[27];
    const float* rb    = (const float*)d_in[28];
    const float* mw    = (const float*)d_in[29];
    const float* mb    = (const float*)d_in[30];

    char* p = (char*)d_ws;
    f16*   shrt16 = (f16*)p;   p += (size_t)65536*128*2;
    f16*   lg16   = (f16*)p;   p += (size_t)262144*2;
    f16*   lgs    = (f16*)p;   p += (size_t)262144*2;
    f16*   la16   = (f16*)p;   p += (size_t)262144*2;
    f16*   Whs    = (f16*)p;   p += (size_t)262144*2;
    f16*   Wcat1  = (f16*)p;   p += (size_t)512*160*2;
    f16*   WcatA  = (f16*)p;   p += (size_t)512*256*2;
    f16*   WT     = (f16*)p;   p += (size_t)16384*2;
    f16*   fwT    = (f16*)p;   p += (size_t)49152*2;
    f16*   ggW16  = (f16*)p;   p += (size_t)49152*2;
    float* el     = (float*)p; p += 2048*4;
    float* ers    = (float*)p; p += 2048*4;
    float* secf   = (float*)p; p += 2048*4;
    float* seco   = (float*)p; p += 2048*4;
    int*   memflat= (int*)p;   p += 2048*4;
    int*   cnt    = (int*)p;   p += 16*4;
    int*   basep  = (int*)p;   p += 16*4;

    // 0. weight prep + bucketing
    prep_kernel<<<865,256,0,stream>>>(g1Wih, g1Whh, gaWih, gaWhh, giW, fw, ggWih, sec,
                                      Wcat1, WcatA, WT, fwT, ggW16, memflat, cnt, basep);
    // 1. short GRU+attn (65536 windows, T=5)
    gru_short<<<4096,512,0,stream>>>(sf, Wcat1, g1bih, g1bhh, a1w, a1b, shrt16);
    // 2. la GRU+attn + gat_prep merged
    la_gatprep<<<320,512,0,stream>>>(shrt16, WcatA, gabih, gabhh, aaw, aab, la16,
                                     WT, gia, memflat, Whs, ers, el);
    // 3. intra-sector GAT + lg (T=1 GRU), sorted-order rows
    gat_intra_lg<<<512,256,0,stream>>>(Whs, ers, el, sec, cnt, basep, memflat,
                                       ggW16, ggbih, ggbhh, lg16, lgs, 2048);
    // 4a. sector means over sorted lgs (16 CUs, coalesced)
    sector_mean_sorted<<<16,128,0,stream>>>(lgs, cnt, basep, secf);
    // 4b. inter-sector GAT (tiny)
    gat_inter_kernel<<<1,256,0,stream>>>(secf, adj, geW, gea, seco);
    // 5. fusion + heads
    fused_mfma<<<64,256,0,stream>>>(lg16, la16, seco, sec, fwT, fb, rw, rb, mw, mb, (float*)d_out);
}

// Round 9
// 420.934 us; speedup vs baseline: 1.5589x; 1.0684x over previous
//
#include <hip/hip_runtime.h>
#include <math.h>

#define LRELU_A 0.2f
#define NEGBIG (-9.0e15f)

typedef _Float16 f16;
typedef _Float16 f16x8 __attribute__((ext_vector_type(8)));
typedef _Float16 f16x4 __attribute__((ext_vector_type(4)));
typedef float floatx4 __attribute__((ext_vector_type(4)));

__device__ __forceinline__ float rcpf(float x){ return __builtin_amdgcn_rcpf(x); }
__device__ __forceinline__ float sigm_f(float x){ return rcpf(1.0f + __expf(-x)); }
__device__ __forceinline__ float tanh_f(float x){ return 1.0f - 2.0f*rcpf(1.0f + __expf(2.0f*x)); }
__device__ __forceinline__ float sigm(float x){ return rcpf(1.0f+__expf(-x)); }
__device__ __forceinline__ f16x8 load_cvt8(const float* __restrict__ p){
    float4 a = *(const float4*)p; float4 b = *(const float4*)(p+4);
    f16x8 r; r[0]=(f16)a.x; r[1]=(f16)a.y; r[2]=(f16)a.z; r[3]=(f16)a.w;
    r[4]=(f16)b.x; r[5]=(f16)b.y; r[6]=(f16)b.z; r[7]=(f16)b.w;
    return r;
}
#define MFMA16(A,B,C) __builtin_amdgcn_mfma_f32_16x16x32_f16((A),(B),(C),0,0,0)

// ---------------------------------------------------------------------------
// prep: Wcat1 | WcatA | WT | fwT | ggW16 | bucket. 865 blocks.
// ---------------------------------------------------------------------------
__global__ __launch_bounds__(256) void prep_kernel(
    const float* __restrict__ g1Wih, const float* __restrict__ g1Whh,
    const float* __restrict__ gaWih, const float* __restrict__ gaWhh,
    const float* __restrict__ giW,   const float* __restrict__ fw,
    const float* __restrict__ ggWih, const int* __restrict__ sec,
    f16* __restrict__ Wcat1, f16* __restrict__ WcatA,
    f16* __restrict__ WT, f16* __restrict__ fwT, f16* __restrict__ ggW16,
    int* __restrict__ memflat, int* __restrict__ cnt, int* __restrict__ base)
{
    __shared__ int cs[16], wsc[16];
    const int b = blockIdx.x, tid = threadIdx.x;
    if (b < 160){                      // Wcat1: INF=16, INFPAD=32, KTOT=160
        for (int idx = b*256+tid; idx < 512*160; idx += 160*256){
            int r = idx/160, k = idx - r*160;
            float v = 0.0f;
            if (r < 256){ if (k < 32){ if (k < 16) v = g1Wih[r*16+k]; } else v = g1Whh[r*128 + (k-32)]; }
            else if (r < 384){ if (k < 16) v = g1Wih[r*16+k]; }
            else { if (k >= 32) v = g1Whh[(r-128)*128 + (k-32)]; }
            Wcat1[idx] = (f16)v;
        }
    } else if (b < 416){               // WcatA: INF=128, KTOT=256
        for (int idx = (b-160)*256+tid; idx < 512*256; idx += 256*256){
            int r = idx >> 8, k = idx & 255;
            float v = 0.0f;
            if (r < 256){ v = (k < 128) ? gaWih[r*128+k] : gaWhh[r*128 + (k-128)]; }
            else if (r < 384){ if (k < 128) v = gaWih[r*128+k]; }
            else { if (k >= 128) v = gaWhh[(r-128)*128 + (k-128)]; }
            WcatA[idx] = (f16)v;
        }
    } else if (b < 480){               // WT = giW^T (128x128)
        int idx = (b-416)*256+tid;
        int r = idx >> 7, c = idx & 127;
        WT[c*128 + r] = (f16)giW[idx];
    } else if (b < 672){               // fwT = fw^T (384x128 -> 128x384)
        int idx = (b-480)*256+tid;
        int r = idx >> 7, c = idx & 127;
        fwT[c*384 + r] = (f16)fw[idx];
    } else if (b < 864){               // ggW16 = (f16)ggWih  [384][128]
        int idx = (b-672)*256+tid;
        ggW16[idx] = (f16)ggWih[idx];
    } else {                           // bucket
        if (tid < 16) cs[tid] = 0;
        __syncthreads();
        for (int s = tid; s < 2048; s += 256) atomicAdd(&cs[sec[s]], 1);
        __syncthreads();
        if (tid == 0){
            int acc = 0;
            for (int g=0; g<16; g++){ cnt[g]=cs[g]; base[g]=acc; wsc[g]=acc; acc+=cs[g]; }
        }
        __syncthreads();
        for (int s = tid; s < 2048; s += 256){
            int g = sec[s];
            int p = atomicAdd(&wsc[g], 1);
            memflat[p] = s;
        }
    }
}

// ---------------------------------------------------------------------------
// Short GRU+attn v4. M=32 seqs/block (2 subtiles), 2048 blocks, 8 waves.
// Direct-global Bx (no xs staging), lagged unnormalized softmax, 1 barrier/step.
// R8 lesson: M=16 doubles per-block fixed cost -> 154us vs 106 (R6 M=32).
// NOTE (512,2): (512,4) caps VGPR at 64 -> massive spill (R5).
// ---------------------------------------------------------------------------
__global__ __launch_bounds__(512,2) void gru_short(
    const float* __restrict__ x, const f16* __restrict__ Wcat,
    const float* __restrict__ bih, const float* __restrict__ bhh,
    const float* __restrict__ aw, const float* __restrict__ ab,
    f16* __restrict__ out)
{
    __shared__ __align__(16) f16 hs[2][32][136];
    __shared__ float scpart[2][8][32];
    const int tid = threadIdx.x, w = tid>>6, lane = tid&63;
    const int c = lane&15, quad = lane>>4;
    const int s0 = blockIdx.x*32;

    { f16x4 z4 = {0,0,0,0};
      f16x4* zh = (f16x4*)&hs[1][0][0];
      for (int i=tid; i<1088; i+=512) zh[i] = z4; }

    auto loadBx = [&](int st, int t)->f16x8 {
        f16x8 bx = {0,0,0,0,0,0,0,0};
        if (quad < 2){
            const float* px = &x[(size_t)(s0+st*16+c)*80 + t*16 + quad*8];
            float4 a = *(const float4*)px, bq = *(const float4*)(px+4);
            bx[0]=(f16)a.x; bx[1]=(f16)a.y; bx[2]=(f16)a.z; bx[3]=(f16)a.w;
            bx[4]=(f16)bq.x; bx[5]=(f16)bq.y; bx[6]=(f16)bq.z; bx[7]=(f16)bq.w;
        }
        return bx;
    };

    const int jrow = w*16 + c;
    f16x8 Ar[5], Az[5], Agi, Agh[4];
#pragma unroll
    for (int kb=0;kb<5;kb++){
        Ar[kb] = *(const f16x8*)&Wcat[(size_t)(jrow)*160 + kb*32 + quad*8];
        Az[kb] = *(const f16x8*)&Wcat[(size_t)(128+jrow)*160 + kb*32 + quad*8];
    }
    Agi = *(const f16x8*)&Wcat[(size_t)(256+jrow)*160 + quad*8];
#pragma unroll
    for (int i=0;i<4;i++)
        Agh[i] = *(const f16x8*)&Wcat[(size_t)(384+jrow)*160 + 32 + i*32 + quad*8];

    float brz_r[4], brz_z[4], b_in[4], b_hn[4], awr[4];
#pragma unroll
    for (int r=0;r<4;r++){
        int j = w*16 + quad*4 + r;
        brz_r[r] = bih[j] + bhh[j];
        brz_z[r] = bih[128+j] + bhh[128+j];
        b_in[r] = bih[256+j]; b_hn[r] = bhh[256+j];
        awr[r] = aw[j];
    }
    const float abv = ab[0];
    float hreg[2][4], aacc[2][4], l_[2] = {0.0f, 0.0f};
#pragma unroll
    for (int st=0; st<2; st++)
#pragma unroll
        for (int r=0;r<4;r++){ hreg[st][r]=0.0f; aacc[st][r]=0.0f; }
    f16x8 bxc[2] = { loadBx(0,0), loadBx(1,0) };
    __syncthreads();

#pragma unroll 1
    for (int t=0; t<5; ++t){
        const int rp = (t&1)^1, wp = t&1;
        f16x8 Bh[2][4];
#pragma unroll
        for (int st=0; st<2; st++)
#pragma unroll
            for (int i=0;i<4;i++)
                Bh[st][i] = *(const f16x8*)&hs[rp][st*16+c][i*32+quad*8];
        f16x8 bxn[2];
        if (t < 4){ bxn[0] = loadBx(0,t+1); bxn[1] = loadBx(1,t+1); }
        // lagged attention: apply step t-1's weight to h_{t-1} (still in hreg)
        if (t > 0){
#pragma unroll
            for (int st=0; st<2; st++){
                float sc = abv;
#pragma unroll
                for (int ww=0; ww<8; ww++) sc += scpart[rp][ww][st*16+c];
                float e = __expf(sc);
                l_[st] += e;
#pragma unroll
                for (int r=0;r<4;r++) aacc[st][r] += e*hreg[st][r];
            }
        }
        float sp[2];
#pragma unroll
        for (int st=0; st<2; st++){
            floatx4 ar = {0,0,0,0}, az = {0,0,0,0}, agi = {0,0,0,0}, agh = {0,0,0,0};
            ar = MFMA16(Ar[0], bxc[st], ar);
            az = MFMA16(Az[0], bxc[st], az);
            agi = MFMA16(Agi, bxc[st], agi);
#pragma unroll
            for (int i=0;i<4;i++){
                ar = MFMA16(Ar[1+i], Bh[st][i], ar);
                az = MFMA16(Az[1+i], Bh[st][i], az);
                agh = MFMA16(Agh[i], Bh[st][i], agh);
            }
            f16x4 h4;
            sp[st] = 0.0f;
#pragma unroll
            for (int r=0;r<4;r++){
                float rg = sigm_f(ar[r] + brz_r[r]);
                float zg = sigm_f(az[r] + brz_z[r]);
                float ng = tanh_f(agi[r] + b_in[r] + rg*(agh[r] + b_hn[r]));
                float hn = fmaf(zg, hreg[st][r] - ng, ng);
                hreg[st][r] = hn; h4[r] = (f16)hn;
                sp[st] += hn * awr[r];
            }
            *(f16x4*)&hs[wp][st*16 + c][w*16 + quad*4] = h4;
        }
#pragma unroll
        for (int st=0; st<2; st++){
            sp[st] += __shfl_xor(sp[st], 16);
            sp[st] += __shfl_xor(sp[st], 32);
        }
        if (lane < 16){ scpart[wp][w][lane] = sp[0]; scpart[wp][w][16+lane] = sp[1]; }
        bxc[0] = bxn[0]; bxc[1] = bxn[1];
        __syncthreads();
    }
    // drain (t=4 wrote scpart[0] and hs[0])
#pragma unroll
    for (int st=0; st<2; st++){
        float sc = abv;
#pragma unroll
        for (int ww=0; ww<8; ww++) sc += scpart[0][ww][st*16+c];
        float e = __expf(sc);
        l_[st] += e;
        float inv = rcpf(l_[st]);
        f16x4 h4;
#pragma unroll
        for (int r=0;r<4;r++) h4[r] = (f16)((aacc[st][r] + e*hreg[st][r])*inv);
        *(f16x4*)&hs[0][st*16 + c][w*16 + quad*4] = h4;
    }
    __syncthreads();
    { int s = tid>>4, p = tid&15;
      *(f16x8*)&out[(size_t)(s0+s)*128 + p*8] = *(const f16x8*)&hs[0][s][p*8]; }
}

// ---------------------------------------------------------------------------
// Merged: blocks 0..255 -> la GRU+attn (M=8 real); 256..319 -> gat_prep.
// ---------------------------------------------------------------------------
__global__ __launch_bounds__(512,2) void la_gatprep(
    const f16* __restrict__ shrt16, const f16* __restrict__ Wcat,
    const float* __restrict__ bih, const float* __restrict__ bhh,
    const float* __restrict__ aw, const float* __restrict__ ab,
    f16* __restrict__ la16,
    const f16* __restrict__ WT, const float* __restrict__ gia,
    const int* __restrict__ memflat,
    f16* __restrict__ Whs, float* __restrict__ ers, float* __restrict__ el)
{
    __shared__ __align__(16) char smem[17152];
    const int tid = threadIdx.x, w = tid>>6, lane = tid&63;
    const int c = lane&15, quad = lane>>4;

    if (blockIdx.x < 256){
        // ---------------- la GRU ----------------
        f16* hsp = (f16*)smem;                        // [2][16][136]
        float* scp = (float*)(smem + 2*16*136*2);     // [2][8][16]
        const int s0 = blockIdx.x*8;
        const int sx = (s0 + c < 2047) ? (s0 + c) : 2047;

        { f16x4 z4 = {0,0,0,0};
          f16x4* zh = (f16x4*)(hsp + 16*136);
          for (int i=tid; i<544; i+=512) zh[i] = z4; }

        const int jrow = w*16 + c;
        f16x8 Ar[8], Az[8], Agi[4], Agh[4];
#pragma unroll
        for (int kb=0;kb<8;kb++){
            Ar[kb] = *(const f16x8*)&Wcat[(size_t)(jrow)*256 + kb*32 + quad*8];
            Az[kb] = *(const f16x8*)&Wcat[(size_t)(128+jrow)*256 + kb*32 + quad*8];
        }
#pragma unroll
        for (int i=0;i<4;i++){
            Agi[i] = *(const f16x8*)&Wcat[(size_t)(256+jrow)*256 + i*32 + quad*8];
            Agh[i] = *(const f16x8*)&Wcat[(size_t)(384+jrow)*256 + 128 + i*32 + quad*8];
        }
        float brz_r[4], brz_z[4], b_in[4], b_hn[4], awr[4];
#pragma unroll
        for (int r=0;r<4;r++){
            int j = w*16 + quad*4 + r;
            brz_r[r] = bih[j] + bhh[j];
            brz_z[r] = bih[128+j] + bhh[128+j];
            b_in[r] = bih[256+j]; b_hn[r] = bhh[256+j];
            awr[r] = aw[j];
        }
        const float abv = ab[0];
        float hreg[4] = {0,0,0,0}, aacc[4] = {0,0,0,0}, l_ = 0.0f;
        f16x8 Bxc[4];
#pragma unroll
        for (int i=0;i<4;i++)
            Bxc[i] = *(const f16x8*)&shrt16[((size_t)sx*32 + 0)*128 + i*32 + quad*8];
        __syncthreads();

#pragma unroll 1
        for (int t=0; t<32; ++t){
            const int rp = (t&1)^1, wp = t&1;
            f16x8 Bh[4];
#pragma unroll
            for (int i=0;i<4;i++)
                Bh[i] = *(const f16x8*)&hsp[((size_t)rp*16 + c)*136 + i*32 + quad*8];
            f16x8 Bxn[4];
            if (t < 31){
#pragma unroll
                for (int i=0;i<4;i++)
                    Bxn[i] = *(const f16x8*)&shrt16[((size_t)sx*32 + t+1)*128 + i*32 + quad*8];
            }
            if (t > 0){
                float sc = abv;
#pragma unroll
                for (int ww=0; ww<8; ww++) sc += scp[(rp*8+ww)*16 + c];
                float e = __expf(sc);
                l_ += e;
#pragma unroll
                for (int r=0;r<4;r++) aacc[r] += e*hreg[r];
            }
            floatx4 ar = {0,0,0,0}, az = {0,0,0,0}, agi = {0,0,0,0}, agh = {0,0,0,0};
#pragma unroll
            for (int i=0;i<4;i++){
                ar = MFMA16(Ar[i], Bxc[i], ar);
                az = MFMA16(Az[i], Bxc[i], az);
                agi = MFMA16(Agi[i], Bxc[i], agi);
            }
#pragma unroll
            for (int i=0;i<4;i++){
                ar = MFMA16(Ar[4+i], Bh[i], ar);
                az = MFMA16(Az[4+i], Bh[i], az);
                agh = MFMA16(Agh[i], Bh[i], agh);
            }
            f16x4 h4;
            float sp = 0.0f;
#pragma unroll
            for (int r=0;r<4;r++){
                float rg = sigm_f(ar[r] + brz_r[r]);
                float zg = sigm_f(az[r] + brz_z[r]);
                float ng = tanh_f(agi[r] + b_in[r] + rg*(agh[r] + b_hn[r]));
                float hn = fmaf(zg, hreg[r] - ng, ng);
                hreg[r] = hn; h4[r] = (f16)hn;
                sp += hn * awr[r];
            }
            *(f16x4*)&hsp[((size_t)wp*16 + c)*136 + w*16 + quad*4] = h4;
            sp += __shfl_xor(sp, 16);
            sp += __shfl_xor(sp, 32);
            if (lane < 16) scp[(wp*8+w)*16 + lane] = sp;
#pragma unroll
            for (int i=0;i<4;i++) Bxc[i] = Bxn[i];
            __syncthreads();
        }
        // drain (t=31 wrote parity 1)
        {
            float sc = abv;
#pragma unroll
            for (int ww=0; ww<8; ww++) sc += scp[(8+ww)*16 + c];
            float e = __expf(sc);
            l_ += e;
            float inv = rcpf(l_);
            f16x4 h4;
#pragma unroll
            for (int r=0;r<4;r++) h4[r] = (f16)((aacc[r] + e*hreg[r])*inv);
            *(f16x4*)&hsp[((size_t)16 + c)*136 + w*16 + quad*4] = h4;
        }
        __syncthreads();
        if (tid < 128){
            int s = tid>>4, p = tid&15;
            *(f16x8*)&la16[(size_t)(s0+s)*128 + p*8] =
                *(const f16x8*)&hsp[((size_t)16 + s)*136 + p*8];
        }
    } else {
        // ---------------- gat_prep (512-thread variant) ----------------
        float* tbuf = (float*)smem;                   // [32][132]
        int* rows = (int*)(smem + 32*132*4);
        const int p0 = (blockIdx.x - 256)*32;
        if (tid < 32) rows[tid] = memflat[p0 + tid];
        __syncthreads();
        f16x8 A[2][4];
#pragma unroll
        for (int mt=0;mt<2;mt++)
#pragma unroll
            for (int kb=0;kb<4;kb++)
                A[mt][kb] = *(const f16x8*)&shrt16[((size_t)rows[mt*16+c]*32 + 31)*128 + kb*32 + quad*8];
        const int jb = w;
        f16x8 B[4];
#pragma unroll
        for (int kb=0;kb<4;kb++)
            B[kb] = *(const f16x8*)&WT[(size_t)(jb*16+c)*128 + kb*32 + quad*8];
        floatx4 acc[2] = {{0,0,0,0},{0,0,0,0}};
#pragma unroll
        for (int kb=0;kb<4;kb++){
            acc[0] = MFMA16(A[0][kb], B[kb], acc[0]);
            acc[1] = MFMA16(A[1][kb], B[kb], acc[1]);
        }
#pragma unroll
        for (int mt=0;mt<2;mt++)
#pragma unroll
            for (int r=0;r<4;r++)
                tbuf[(mt*16 + quad*4 + r)*132 + jb*16 + c] = acc[mt][r];
        __syncthreads();
        for (int i=tid; i<1024; i+=512){
            int s = i>>5, p = i&31;
            float4 v = *(const float4*)&tbuf[s*132 + p*4];
            f16x4 h4; h4[0]=(f16)v.x; h4[1]=(f16)v.y; h4[2]=(f16)v.z; h4[3]=(f16)v.w;
            *(f16x4*)&Whs[(size_t)(p0+s)*128 + p*4] = h4;
        }
#pragma unroll
        for (int k=0; k<4; k++){
            int row = w*4 + k;
            float w0 = tbuf[row*132 + lane], w1 = tbuf[row*132 + 64 + lane];
            float v1 = w0*gia[lane]     + w1*gia[64+lane];
            float v2 = w0*gia[128+lane] + w1*gia[192+lane];
#pragma unroll
            for (int off=32; off; off>>=1){ v1 += __shfl_down(v1,off); v2 += __shfl_down(v2,off); }
            if (lane==0){ el[rows[row]] = v1; ers[p0+row] = v2; }
        }
    }
}

// ---------------------------------------------------------------------------
// GAT intra + fused T=1 lg GRU. One wave per SORTED row p.
// ---------------------------------------------------------------------------
__global__ __launch_bounds__(256) void gat_intra_lg(
    const f16* __restrict__ Whs, const float* __restrict__ ers,
    const float* __restrict__ el, const int* __restrict__ sec,
    const int* __restrict__ cnt, const int* __restrict__ base,
    const int* __restrict__ memflat,
    const f16* __restrict__ ggW16,
    const float* __restrict__ ggbih, const float* __restrict__ ggbhh,
    f16* __restrict__ lgout, f16* __restrict__ lgs, int S)
{
    __shared__ __align__(16) f16 irow[4][136];
    int wave = threadIdx.x>>6, lane = threadIdx.x&63;
    int p = blockIdx.x*4 + wave;
    if (p>=S) return;
    int i = memflat[p];
    int g = sec[i];
    int n = cnt[g], b = base[g];
    float eli = el[i];
    float m = -INFINITY;
    for (int jj=lane; jj<n; jj+=64){
        float v = eli + ers[b+jj]; v = v>0.f? v : LRELU_A*v;
        m = fmaxf(m, v);
    }
#pragma unroll
    for (int off=32; off; off>>=1) m = fmaxf(m, __shfl_xor(m, off));
    float l = 0.f, c0=0.f, c1=0.f;
#pragma unroll 4
    for (int jj=0; jj<n; jj++){
        float v = eli + ers[b+jj]; v = v>0.f? v : LRELU_A*v;
        float pw = __expf(v-m);
        l += pw;
        c0 += pw*(float)Whs[(size_t)(b+jj)*128 + lane];
        c1 += pw*(float)Whs[(size_t)(b+jj)*128 + 64 + lane];
    }
    float il = rcpf(l);
    c0 *= il; c1 *= il;
    float e0 = c0>0.f? c0 : expm1f(c0);
    float e1 = c1>0.f? c1 : expm1f(c1);
    irow[wave][lane] = (f16)e0;
    irow[wave][64+lane] = (f16)e1;
    float sr0=0,sr1=0,sz0=0,sz1=0,sn0=0,sn1=0;
    const int j0 = lane, j1 = 64 + lane;
#pragma unroll 4
    for (int kb=0; kb<16; kb++){
        f16x8 hv = *(const f16x8*)&irow[wave][kb*8];
        f16x8 wr0 = *(const f16x8*)&ggW16[(size_t)(j0)*128 + kb*8];
        f16x8 wr1 = *(const f16x8*)&ggW16[(size_t)(j1)*128 + kb*8];
        f16x8 wz0 = *(const f16x8*)&ggW16[(size_t)(128+j0)*128 + kb*8];
        f16x8 wz1 = *(const f16x8*)&ggW16[(size_t)(128+j1)*128 + kb*8];
        f16x8 wn0 = *(const f16x8*)&ggW16[(size_t)(256+j0)*128 + kb*8];
        f16x8 wn1 = *(const f16x8*)&ggW16[(size_t)(256+j1)*128 + kb*8];
#pragma unroll
        for (int e=0;e<8;e++){
            float h = (float)hv[e];
            sr0 = fmaf(h, (float)wr0[e], sr0);
            sr1 = fmaf(h, (float)wr1[e], sr1);
            sz0 = fmaf(h, (float)wz0[e], sz0);
            sz1 = fmaf(h, (float)wz1[e], sz1);
            sn0 = fmaf(h, (float)wn0[e], sn0);
            sn1 = fmaf(h, (float)wn1[e], sn1);
        }
    }
    float r0 = sigm_f(sr0 + ggbih[j0] + ggbhh[j0]);
    float r1 = sigm_f(sr1 + ggbih[j1] + ggbhh[j1]);
    float z0 = sigm_f(sz0 + ggbih[128+j0] + ggbhh[128+j0]);
    float z1 = sigm_f(sz1 + ggbih[128+j1] + ggbhh[128+j1]);
    float n0 = tanh_f(sn0 + ggbih[256+j0] + r0*ggbhh[256+j0]);
    float n1 = tanh_f(sn1 + ggbih[256+j1] + r1*ggbhh[256+j1]);
    f16 v0 = (f16)((1.0f - z0)*n0);
    f16 v1 = (f16)((1.0f - z1)*n1);
    lgout[(size_t)i*128 + j0] = v0;
    lgout[(size_t)i*128 + j1] = v1;
    lgs[(size_t)p*128 + j0] = v0;
    lgs[(size_t)p*128 + j1] = v1;
}

// sector means over SORTED lgs: block g, thread j, contiguous stream
__global__ __launch_bounds__(128) void sector_mean_sorted(
    const f16* __restrict__ lgs, const int* __restrict__ cnt,
    const int* __restrict__ base, float* __restrict__ secf)
{
    int g = blockIdx.x, j = threadIdx.x;
    int n = cnt[g], b = base[g];
    float sum=0.f;
    for (int k=0;k<n;k++) sum += (float)lgs[(size_t)(b+k)*128 + j];
    secf[g*128+j] = sum * rcpf(fmaxf((float)n,1.0f));
}

__global__ __launch_bounds__(256) void gat_inter_kernel(
    const float* __restrict__ secf, const int* __restrict__ adj,
    const float* __restrict__ W, const float* __restrict__ a,
    float* __restrict__ outp)
{
    __shared__ __align__(16) float hsf[16][132];
    __shared__ __align__(16) float Whq[16][132];
    __shared__ float elq[16], erq[16], att[16][16];
    const int tid=threadIdx.x;
    for (int idx=tid; idx<2048; idx+=256){ int s=idx>>7,j=idx&127; hsf[s][j]=secf[idx]; }
    __syncthreads();
#pragma unroll 1
    for (int i=0;i<8;i++){
        int idx=i*256+tid; int o=idx&127, s=idx>>7;
        float a0=0.f,a1=0.f,a2=0.f,a3=0.f;
        for (int j=0;j<128;j+=4){
            a0 += hsf[s][j]  *W[(j  )*128+o];
            a1 += hsf[s][j+1]*W[(j+1)*128+o];
            a2 += hsf[s][j+2]*W[(j+2)*128+o];
            a3 += hsf[s][j+3]*W[(j+3)*128+o];
        }
        Whq[s][o]=(a0+a1)+(a2+a3);
    }
    __syncthreads();
    if (tid<32){
        int s=tid&15; int second = tid>>4;
        const float* av = a + (second?128:0);
        float acc=0.f; for(int o=0;o<128;o++) acc += Whq[s][o]*av[o];
        if (second) erq[s]=acc; else elq[s]=acc;
    }
    __syncthreads();
    if (tid<16){
        int i=tid; float m=NEGBIG; float e[16];
        for(int j=0;j<16;j++){
            float v = elq[i]+erq[j]; v = v>0.f? v : LRELU_A*v;
            e[j] = (adj[i*16+j]>0)? v : NEGBIG;
            m = fmaxf(m,e[j]);
        }
        float l=0.f;
        for(int j=0;j<16;j++){ float p=__expf(e[j]-m); att[i][j]=p; l+=p; }
        float il = rcpf(l);
        for(int j=0;j<16;j++) att[i][j] *= il;
    }
    __syncthreads();
#pragma unroll
    for (int i=0;i<8;i++){
        int idx=i*256+tid; int o=idx&127, s=idx>>7;
        float acc=0.f;
#pragma unroll
        for(int j=0;j<16;j++) acc += att[s][j]*Whq[j][o];
        outp[s*128+o] = acc>0.f? acc : expm1f(acc);
    }
}

// ---------------------------------------------------------------------------
// fused = [lg|la|sec_ps] @ fw + fb, then both heads in-kernel
// ---------------------------------------------------------------------------
__global__ __launch_bounds__(256) void fused_mfma(
    const f16* __restrict__ lg16, const f16* __restrict__ la16,
    const float* __restrict__ seco, const int* __restrict__ sec,
    const f16* __restrict__ fwT,
    const float* __restrict__ fb, const float* __restrict__ rw,
    const float* __restrict__ rb, const float* __restrict__ mw,
    const float* __restrict__ mb, float* __restrict__ outp)
{
    __shared__ float rpart[4][32], mpart[4][32];
    const int tid = threadIdx.x, w = tid>>6, lane = tid&63;
    const int c = lane&15, quad = lane>>4;
    const int s0 = blockIdx.x*32;
    f16x8 A[2][12];
#pragma unroll
    for (int mt=0;mt<2;mt++){
        int row = s0 + mt*16 + c;
        int g = sec[row];
#pragma unroll
        for (int kb=0;kb<4;kb++){
            A[mt][kb]   = *(const f16x8*)&lg16[(size_t)row*128 + kb*32 + quad*8];
            A[mt][4+kb] = *(const f16x8*)&la16[(size_t)row*128 + kb*32 + quad*8];
            A[mt][8+kb] = load_cvt8(&seco[(size_t)g*128 + kb*32 + quad*8]);
        }
    }
    float rsum[2][4] = {{0,0,0,0},{0,0,0,0}};
    float msum[2][4] = {{0,0,0,0},{0,0,0,0}};
#pragma unroll
    for (int i=0;i<2;i++){
        int jb = w*2 + i;
        int col = jb*16 + c;
        f16x8 B[12];
#pragma unroll
        for (int kb=0;kb<12;kb++)
            B[kb] = *(const f16x8*)&fwT[(size_t)col*384 + kb*32 + quad*8];
        floatx4 acc[2] = {{0,0,0,0},{0,0,0,0}};
#pragma unroll
        for (int kb=0;kb<12;kb++){
            acc[0] = MFMA16(A[0][kb], B[kb], acc[0]);
            acc[1] = MFMA16(A[1][kb], B[kb], acc[1]);
        }
        float fbv = fb[col], rwv = rw[col], mwv = mw[col];
#pragma unroll
        for (int mt=0;mt<2;mt++)
#pragma unroll
            for (int r=0;r<4;r++){
                float fu = acc[mt][r] + fbv;
                rsum[mt][r] += fu*rwv;
                msum[mt][r] += fu*mwv;
            }
    }
#pragma unroll
    for (int mt=0;mt<2;mt++)
#pragma unroll
        for (int r=0;r<4;r++){
#pragma unroll
            for (int off=1; off<16; off<<=1){
                rsum[mt][r] += __shfl_xor(rsum[mt][r], off);
                msum[mt][r] += __shfl_xor(msum[mt][r], off);
            }
            if (c==0){
                rpart[w][mt*16 + quad*4 + r] = rsum[mt][r];
                mpart[w][mt*16 + quad*4 + r] = msum[mt][r];
            }
        }
    __syncthreads();
    if (tid < 32){
        int s = tid;
        float rs = rb[0], ms = mb[0];
#pragma unroll
        for (int ww=0; ww<4; ww++){ rs += rpart[ww][s]; ms += mpart[ww][s]; }
        outp[s0+s] = rs;
        outp[2048 + s0 + s] = sigm(ms);
    }
}

extern "C" void kernel_launch(void* const* d_in, const int* in_sizes, int n_in,
                              void* d_out, int out_size, void* d_ws, size_t ws_size,
                              hipStream_t stream) {
    const float* sf    = (const float*)d_in[0];
    const int*   sec   = (const int*)  d_in[1];
    const int*   adj   = (const int*)  d_in[2];
    const float* g1Wih = (const float*)d_in[3];
    const float* g1Whh = (const float*)d_in[4];
    const float* g1bih = (const float*)d_in[5];
    const float* g1bhh = (const float*)d_in[6];
    const float* a1w   = (const float*)d_in[7];
    const float* a1b   = (const float*)d_in[8];
    const float* giW   = (const float*)d_in[9];
    const float* gia   = (const float*)d_in[10];
    const float* ggWih = (const float*)d_in[11];
    const float* ggbih = (const float*)d_in[13];
    const float* ggbhh = (const float*)d_in[14];
    const float* gaWih = (const float*)d_in[17];
    const float* gaWhh = (const float*)d_in[18];
    const float* gabih = (const float*)d_in[19];
    const float* gabhh = (const float*)d_in[20];
    const float* aaw   = (const float*)d_in[21];
    const float* aab   = (const float*)d_in[22];
    const float* geW   = (const float*)d_in[23];
    const float* gea   = (const float*)d_in[24];
    const float* fw    = (const float*)d_in[25];
    const float* fb    = (const float*)d_in[26];
    const float* rw    = (const float*)d_in[27];
    const float* rb    = (const float*)d_in[28];
    const float* mw    = (const float*)d_in[29];
    const float* mb    = (const float*)d_in[30];

    char* p = (char*)d_ws;
    f16*   shrt16 = (f16*)p;   p += (size_t)65536*128*2;
    f16*   lg16   = (f16*)p;   p += (size_t)262144*2;
    f16*   lgs    = (f16*)p;   p += (size_t)262144*2;
    f16*   la16   = (f16*)p;   p += (size_t)262144*2;
    f16*   Whs    = (f16*)p;   p += (size_t)262144*2;
    f16*   Wcat1  = (f16*)p;   p += (size_t)512*160*2;
    f16*   WcatA  = (f16*)p;   p += (size_t)512*256*2;
    f16*   WT     = (f16*)p;   p += (size_t)16384*2;
    f16*   fwT    = (f16*)p;   p += (size_t)49152*2;
    f16*   ggW16  = (f16*)p;   p += (size_t)49152*2;
    float* el     = (float*)p; p += 2048*4;
    float* ers    = (float*)p; p += 2048*4;
    float* secf   = (float*)p; p += 2048*4;
    float* seco   = (float*)p; p += 2048*4;
    int*   memflat= (int*)p;   p += 2048*4;
    int*   cnt    = (int*)p;   p += 16*4;
    int*   basep  = (int*)p;   p += 16*4;

    // 0. weight prep + bucketing
    prep_kernel<<<865,256,0,stream>>>(g1Wih, g1Whh, gaWih, gaWhh, giW, fw, ggWih, sec,
                                      Wcat1, WcatA, WT, fwT, ggW16, memflat, cnt, basep);
    // 1. short GRU+attn (65536 windows, T=5), M=32/block
    gru_short<<<2048,512,0,stream>>>(sf, Wcat1, g1bih, g1bhh, a1w, a1b, shrt16);
    // 2. la GRU+attn + gat_prep merged
    la_gatprep<<<320,512,0,stream>>>(shrt16, WcatA, gabih, gabhh, aaw, aab, la16,
                                     WT, gia, memflat, Whs, ers, el);
    // 3. intra-sector GAT + lg (T=1 GRU), sorted-order rows
    gat_intra_lg<<<512,256,0,stream>>>(Whs, ers, el, sec, cnt, basep, memflat,
                                       ggW16, ggbih, ggbhh, lg16, lgs, 2048);
    // 4a. sector means over sorted lgs (16 CUs, coalesced)
    sector_mean_sorted<<<16,128,0,stream>>>(lgs, cnt, basep, secf);
    // 4b. inter-sector GAT (tiny)
    gat_inter_kernel<<<1,256,0,stream>>>(secf, adj, geW, gea, seco);
    // 5. fusion + heads
    fused_mfma<<<64,256,0,stream>>>(lg16, la16, seco, sec, fwT, fb, rw, rb, mw, mb, (float*)d_out);
}

// Round 10
// 387.186 us; speedup vs baseline: 1.6948x; 1.0872x over previous
//
#include <hip/hip_runtime.h>
#include <math.h>

#define LRELU_A 0.2f
#define NEGBIG (-9.0e15f)

typedef _Float16 f16;
typedef _Float16 f16x8 __attribute__((ext_vector_type(8)));
typedef _Float16 f16x4 __attribute__((ext_vector_type(4)));
typedef float floatx4 __attribute__((ext_vector_type(4)));

__device__ __forceinline__ float rcpf(float x){ return __builtin_amdgcn_rcpf(x); }
__device__ __forceinline__ float sigm_f(float x){ return rcpf(1.0f + __expf(-x)); }
__device__ __forceinline__ float tanh_f(float x){ return 1.0f - 2.0f*rcpf(1.0f + __expf(2.0f*x)); }
__device__ __forceinline__ float sigm(float x){ return rcpf(1.0f+__expf(-x)); }
__device__ __forceinline__ f16x8 load_cvt8(const float* __restrict__ p){
    float4 a = *(const float4*)p; float4 b = *(const float4*)(p+4);
    f16x8 r; r[0]=(f16)a.x; r[1]=(f16)a.y; r[2]=(f16)a.z; r[3]=(f16)a.w;
    r[4]=(f16)b.x; r[5]=(f16)b.y; r[6]=(f16)b.z; r[7]=(f16)b.w;
    return r;
}
#define MFMA16(A,B,C) __builtin_amdgcn_mfma_f32_16x16x32_f16((A),(B),(C),0,0,0)

// ---------------------------------------------------------------------------
// prep: Wcat1 | WcatA | WT | fwT | ggW16 | bucket. 865 blocks.
// ---------------------------------------------------------------------------
__global__ __launch_bounds__(256) void prep_kernel(
    const float* __restrict__ g1Wih, const float* __restrict__ g1Whh,
    const float* __restrict__ gaWih, const float* __restrict__ gaWhh,
    const float* __restrict__ giW,   const float* __restrict__ fw,
    const float* __restrict__ ggWih, const int* __restrict__ sec,
    f16* __restrict__ Wcat1, f16* __restrict__ WcatA,
    f16* __restrict__ WT, f16* __restrict__ fwT, f16* __restrict__ ggW16,
    int* __restrict__ memflat, int* __restrict__ cnt, int* __restrict__ base)
{
    __shared__ int cs[16], wsc[16];
    const int b = blockIdx.x, tid = threadIdx.x;
    if (b < 160){                      // Wcat1: INF=16, INFPAD=32, KTOT=160
        for (int idx = b*256+tid; idx < 512*160; idx += 160*256){
            int r = idx/160, k = idx - r*160;
            float v = 0.0f;
            if (r < 256){ if (k < 32){ if (k < 16) v = g1Wih[r*16+k]; } else v = g1Whh[r*128 + (k-32)]; }
            else if (r < 384){ if (k < 16) v = g1Wih[r*16+k]; }
            else { if (k >= 32) v = g1Whh[(r-128)*128 + (k-32)]; }
            Wcat1[idx] = (f16)v;
        }
    } else if (b < 416){               // WcatA: INF=128, KTOT=256
        for (int idx = (b-160)*256+tid; idx < 512*256; idx += 256*256){
            int r = idx >> 8, k = idx & 255;
            float v = 0.0f;
            if (r < 256){ v = (k < 128) ? gaWih[r*128+k] : gaWhh[r*128 + (k-128)]; }
            else if (r < 384){ if (k < 128) v = gaWih[r*128+k]; }
            else { if (k >= 128) v = gaWhh[(r-128)*128 + (k-128)]; }
            WcatA[idx] = (f16)v;
        }
    } else if (b < 480){               // WT = giW^T (128x128)
        int idx = (b-416)*256+tid;
        int r = idx >> 7, c = idx & 127;
        WT[c*128 + r] = (f16)giW[idx];
    } else if (b < 672){               // fwT = fw^T (384x128 -> 128x384)
        int idx = (b-480)*256+tid;
        int r = idx >> 7, c = idx & 127;
        fwT[c*384 + r] = (f16)fw[idx];
    } else if (b < 864){               // ggW16 = (f16)ggWih  [384][128]
        int idx = (b-672)*256+tid;
        ggW16[idx] = (f16)ggWih[idx];
    } else {                           // bucket
        if (tid < 16) cs[tid] = 0;
        __syncthreads();
        for (int s = tid; s < 2048; s += 256) atomicAdd(&cs[sec[s]], 1);
        __syncthreads();
        if (tid == 0){
            int acc = 0;
            for (int g=0; g<16; g++){ cnt[g]=cs[g]; base[g]=acc; wsc[g]=acc; acc+=cs[g]; }
        }
        __syncthreads();
        for (int s = tid; s < 2048; s += 256){
            int g = sec[s];
            int p = atomicAdd(&wsc[g], 1);
            memflat[p] = s;
        }
    }
}

// ---------------------------------------------------------------------------
// Short GRU+attn v5. M=64 seqs/block (4 subtiles), 1024 blocks, 8 waves.
// Full xs LDS staging (R9 lesson: staged beats direct-global Bx),
// M as large as regs allow (R8 lesson: fixed cost amortizes with M),
// lagged unnormalized softmax, 1 barrier/step.
// NOTE (512,2): (512,4) caps VGPR at 64 -> massive spill (R5).
// ---------------------------------------------------------------------------
__global__ __launch_bounds__(512,2) void gru_short(
    const float* __restrict__ x, const f16* __restrict__ Wcat,
    const float* __restrict__ bih, const float* __restrict__ bhh,
    const float* __restrict__ aw, const float* __restrict__ ab,
    f16* __restrict__ out)
{
    __shared__ __align__(16) f16 xs[5][64][40];     // cols 16..39 zero
    __shared__ __align__(16) f16 hs[2][64][136];
    __shared__ float scpart[2][8][64];
    const int tid = threadIdx.x, w = tid>>6, lane = tid&63;
    const int c = lane&15, quad = lane>>4;
    const int s0 = blockIdx.x*64;

    { f16x4 z4 = {0,0,0,0};
      f16x4* zx = (f16x4*)&xs[0][0][0];
      for (int i=tid; i<3200; i+=512) zx[i] = z4;
      f16x4* zh = (f16x4*)&hs[1][0][0];
      for (int i=tid; i<2176; i+=512) zh[i] = z4; }
    // stage all x (5 t): 64 seqs x 20 float4
    for (int i=tid; i<1280; i+=512){
        int s = i/20, q = i - 20*s;
        float4 v = *(const float4*)&x[(size_t)(s0+s)*80 + q*4];
        int t = (q*4)>>4, f = (q*4)&15;
        f16x4 h4; h4[0]=(f16)v.x; h4[1]=(f16)v.y; h4[2]=(f16)v.z; h4[3]=(f16)v.w;
        *(f16x4*)&xs[t][s][f] = h4;
    }
    const int jrow = w*16 + c;
    f16x8 Ar[5], Az[5], Agi, Agh[4];
#pragma unroll
    for (int kb=0;kb<5;kb++){
        Ar[kb] = *(const f16x8*)&Wcat[(size_t)(jrow)*160 + kb*32 + quad*8];
        Az[kb] = *(const f16x8*)&Wcat[(size_t)(128+jrow)*160 + kb*32 + quad*8];
    }
    Agi = *(const f16x8*)&Wcat[(size_t)(256+jrow)*160 + quad*8];
#pragma unroll
    for (int i=0;i<4;i++)
        Agh[i] = *(const f16x8*)&Wcat[(size_t)(384+jrow)*160 + 32 + i*32 + quad*8];

    float brz_r[4], brz_z[4], b_in[4], b_hn[4], awr[4];
#pragma unroll
    for (int r=0;r<4;r++){
        int j = w*16 + quad*4 + r;
        brz_r[r] = bih[j] + bhh[j];
        brz_z[r] = bih[128+j] + bhh[128+j];
        b_in[r] = bih[256+j]; b_hn[r] = bhh[256+j];
        awr[r] = aw[j];
    }
    const float abv = ab[0];
    float hreg[4][4], aacc[4][4], l_[4] = {0.0f,0.0f,0.0f,0.0f};
#pragma unroll
    for (int st=0; st<4; st++)
#pragma unroll
        for (int r=0;r<4;r++){ hreg[st][r]=0.0f; aacc[st][r]=0.0f; }
    __syncthreads();

#pragma unroll 1
    for (int t=0; t<5; ++t){
        const int rp = (t&1)^1, wp = t&1;
        // lagged attention: apply step t-1's weight to h_{t-1}
        if (t > 0){
#pragma unroll
            for (int st=0; st<4; st++){
                float sc = abv;
#pragma unroll
                for (int ww=0; ww<8; ww++) sc += scpart[rp][ww][st*16+c];
                float e = __expf(sc);
                l_[st] += e;
#pragma unroll
                for (int r=0;r<4;r++) aacc[st][r] += e*hreg[st][r];
            }
        }
        float sp[4];
#pragma unroll
        for (int st=0; st<4; st++){
            f16x8 Bx = *(const f16x8*)&xs[t][st*16+c][quad*8];
            f16x8 Bh[4];
#pragma unroll
            for (int i=0;i<4;i++)
                Bh[i] = *(const f16x8*)&hs[rp][st*16+c][i*32+quad*8];
            floatx4 ar = {0,0,0,0}, az = {0,0,0,0}, agi = {0,0,0,0}, agh = {0,0,0,0};
            ar = MFMA16(Ar[0], Bx, ar);
            az = MFMA16(Az[0], Bx, az);
            agi = MFMA16(Agi, Bx, agi);
#pragma unroll
            for (int i=0;i<4;i++){
                ar = MFMA16(Ar[1+i], Bh[i], ar);
                az = MFMA16(Az[1+i], Bh[i], az);
                agh = MFMA16(Agh[i], Bh[i], agh);
            }
            f16x4 h4;
            sp[st] = 0.0f;
#pragma unroll
            for (int r=0;r<4;r++){
                float rg = sigm_f(ar[r] + brz_r[r]);
                float zg = sigm_f(az[r] + brz_z[r]);
                float ng = tanh_f(agi[r] + b_in[r] + rg*(agh[r] + b_hn[r]));
                float hn = fmaf(zg, hreg[st][r] - ng, ng);
                hreg[st][r] = hn; h4[r] = (f16)hn;
                sp[st] += hn * awr[r];
            }
            *(f16x4*)&hs[wp][st*16 + c][w*16 + quad*4] = h4;
        }
#pragma unroll
        for (int st=0; st<4; st++){
            sp[st] += __shfl_xor(sp[st], 16);
            sp[st] += __shfl_xor(sp[st], 32);
        }
        if (lane < 16){
#pragma unroll
            for (int st=0; st<4; st++) scpart[wp][w][st*16+lane] = sp[st];
        }
        __syncthreads();
    }
    // drain (t=4 wrote scpart[0] and hs[0])
#pragma unroll
    for (int st=0; st<4; st++){
        float sc = abv;
#pragma unroll
        for (int ww=0; ww<8; ww++) sc += scpart[0][ww][st*16+c];
        float e = __expf(sc);
        l_[st] += e;
        float inv = rcpf(l_[st]);
        f16x4 h4;
#pragma unroll
        for (int r=0;r<4;r++) h4[r] = (f16)((aacc[st][r] + e*hreg[st][r])*inv);
        *(f16x4*)&hs[0][st*16 + c][w*16 + quad*4] = h4;
    }
    __syncthreads();
    for (int i=tid; i<1024; i+=512){
        int s = i>>4, p = i&15;
        *(f16x8*)&out[(size_t)(s0+s)*128 + p*8] = *(const f16x8*)&hs[0][s][p*8];
    }
}

// ---------------------------------------------------------------------------
// Merged: blocks 0..255 -> la GRU+attn (M=8 real); 256..319 -> gat_prep.
// ---------------------------------------------------------------------------
__global__ __launch_bounds__(512,2) void la_gatprep(
    const f16* __restrict__ shrt16, const f16* __restrict__ Wcat,
    const float* __restrict__ bih, const float* __restrict__ bhh,
    const float* __restrict__ aw, const float* __restrict__ ab,
    f16* __restrict__ la16,
    const f16* __restrict__ WT, const float* __restrict__ gia,
    const int* __restrict__ memflat,
    f16* __restrict__ Whs, float* __restrict__ ers, float* __restrict__ el)
{
    __shared__ __align__(16) char smem[17152];
    const int tid = threadIdx.x, w = tid>>6, lane = tid&63;
    const int c = lane&15, quad = lane>>4;

    if (blockIdx.x < 256){
        // ---------------- la GRU ----------------
        f16* hsp = (f16*)smem;                        // [2][16][136]
        float* scp = (float*)(smem + 2*16*136*2);     // [2][8][16]
        const int s0 = blockIdx.x*8;
        const int sx = (s0 + c < 2047) ? (s0 + c) : 2047;

        { f16x4 z4 = {0,0,0,0};
          f16x4* zh = (f16x4*)(hsp + 16*136);
          for (int i=tid; i<544; i+=512) zh[i] = z4; }

        const int jrow = w*16 + c;
        f16x8 Ar[8], Az[8], Agi[4], Agh[4];
#pragma unroll
        for (int kb=0;kb<8;kb++){
            Ar[kb] = *(const f16x8*)&Wcat[(size_t)(jrow)*256 + kb*32 + quad*8];
            Az[kb] = *(const f16x8*)&Wcat[(size_t)(128+jrow)*256 + kb*32 + quad*8];
        }
#pragma unroll
        for (int i=0;i<4;i++){
            Agi[i] = *(const f16x8*)&Wcat[(size_t)(256+jrow)*256 + i*32 + quad*8];
            Agh[i] = *(const f16x8*)&Wcat[(size_t)(384+jrow)*256 + 128 + i*32 + quad*8];
        }
        float brz_r[4], brz_z[4], b_in[4], b_hn[4], awr[4];
#pragma unroll
        for (int r=0;r<4;r++){
            int j = w*16 + quad*4 + r;
            brz_r[r] = bih[j] + bhh[j];
            brz_z[r] = bih[128+j] + bhh[128+j];
            b_in[r] = bih[256+j]; b_hn[r] = bhh[256+j];
            awr[r] = aw[j];
        }
        const float abv = ab[0];
        float hreg[4] = {0,0,0,0}, aacc[4] = {0,0,0,0}, l_ = 0.0f;
        f16x8 Bxc[4];
#pragma unroll
        for (int i=0;i<4;i++)
            Bxc[i] = *(const f16x8*)&shrt16[((size_t)sx*32 + 0)*128 + i*32 + quad*8];
        __syncthreads();

#pragma unroll 1
        for (int t=0; t<32; ++t){
            const int rp = (t&1)^1, wp = t&1;
            f16x8 Bh[4];
#pragma unroll
            for (int i=0;i<4;i++)
                Bh[i] = *(const f16x8*)&hsp[((size_t)rp*16 + c)*136 + i*32 + quad*8];
            f16x8 Bxn[4];
            if (t < 31){
#pragma unroll
                for (int i=0;i<4;i++)
                    Bxn[i] = *(const f16x8*)&shrt16[((size_t)sx*32 + t+1)*128 + i*32 + quad*8];
            }
            if (t > 0){
                float sc = abv;
#pragma unroll
                for (int ww=0; ww<8; ww++) sc += scp[(rp*8+ww)*16 + c];
                float e = __expf(sc);
                l_ += e;
#pragma unroll
                for (int r=0;r<4;r++) aacc[r] += e*hreg[r];
            }
            floatx4 ar = {0,0,0,0}, az = {0,0,0,0}, agi = {0,0,0,0}, agh = {0,0,0,0};
#pragma unroll
            for (int i=0;i<4;i++){
                ar = MFMA16(Ar[i], Bxc[i], ar);
                az = MFMA16(Az[i], Bxc[i], az);
                agi = MFMA16(Agi[i], Bxc[i], agi);
            }
#pragma unroll
            for (int i=0;i<4;i++){
                ar = MFMA16(Ar[4+i], Bh[i], ar);
                az = MFMA16(Az[4+i], Bh[i], az);
                agh = MFMA16(Agh[i], Bh[i], agh);
            }
            f16x4 h4;
            float sp = 0.0f;
#pragma unroll
            for (int r=0;r<4;r++){
                float rg = sigm_f(ar[r] + brz_r[r]);
                float zg = sigm_f(az[r] + brz_z[r]);
                float ng = tanh_f(agi[r] + b_in[r] + rg*(agh[r] + b_hn[r]));
                float hn = fmaf(zg, hreg[r] - ng, ng);
                hreg[r] = hn; h4[r] = (f16)hn;
                sp += hn * awr[r];
            }
            *(f16x4*)&hsp[((size_t)wp*16 + c)*136 + w*16 + quad*4] = h4;
            sp += __shfl_xor(sp, 16);
            sp += __shfl_xor(sp, 32);
            if (lane < 16) scp[(wp*8+w)*16 + lane] = sp;
#pragma unroll
            for (int i=0;i<4;i++) Bxc[i] = Bxn[i];
            __syncthreads();
        }
        // drain (t=31 wrote parity 1)
        {
            float sc = abv;
#pragma unroll
            for (int ww=0; ww<8; ww++) sc += scp[(8+ww)*16 + c];
            float e = __expf(sc);
            l_ += e;
            float inv = rcpf(l_);
            f16x4 h4;
#pragma unroll
            for (int r=0;r<4;r++) h4[r] = (f16)((aacc[r] + e*hreg[r])*inv);
            *(f16x4*)&hsp[((size_t)16 + c)*136 + w*16 + quad*4] = h4;
        }
        __syncthreads();
        if (tid < 128){
            int s = tid>>4, p = tid&15;
            *(f16x8*)&la16[(size_t)(s0+s)*128 + p*8] =
                *(const f16x8*)&hsp[((size_t)16 + s)*136 + p*8];
        }
    } else {
        // ---------------- gat_prep (512-thread variant) ----------------
        float* tbuf = (float*)smem;                   // [32][132]
        int* rows = (int*)(smem + 32*132*4);
        const int p0 = (blockIdx.x - 256)*32;
        if (tid < 32) rows[tid] = memflat[p0 + tid];
        __syncthreads();
        f16x8 A[2][4];
#pragma unroll
        for (int mt=0;mt<2;mt++)
#pragma unroll
            for (int kb=0;kb<4;kb++)
                A[mt][kb] = *(const f16x8*)&shrt16[((size_t)rows[mt*16+c]*32 + 31)*128 + kb*32 + quad*8];
        const int jb = w;
        f16x8 B[4];
#pragma unroll
        for (int kb=0;kb<4;kb++)
            B[kb] = *(const f16x8*)&WT[(size_t)(jb*16+c)*128 + kb*32 + quad*8];
        floatx4 acc[2] = {{0,0,0,0},{0,0,0,0}};
#pragma unroll
        for (int kb=0;kb<4;kb++){
            acc[0] = MFMA16(A[0][kb], B[kb], acc[0]);
            acc[1] = MFMA16(A[1][kb], B[kb], acc[1]);
        }
#pragma unroll
        for (int mt=0;mt<2;mt++)
#pragma unroll
            for (int r=0;r<4;r++)
                tbuf[(mt*16 + quad*4 + r)*132 + jb*16 + c] = acc[mt][r];
        __syncthreads();
        for (int i=tid; i<1024; i+=512){
            int s = i>>5, p = i&31;
            float4 v = *(const float4*)&tbuf[s*132 + p*4];
            f16x4 h4; h4[0]=(f16)v.x; h4[1]=(f16)v.y; h4[2]=(f16)v.z; h4[3]=(f16)v.w;
            *(f16x4*)&Whs[(size_t)(p0+s)*128 + p*4] = h4;
        }
#pragma unroll
        for (int k=0; k<4; k++){
            int row = w*4 + k;
            float w0 = tbuf[row*132 + lane], w1 = tbuf[row*132 + 64 + lane];
            float v1 = w0*gia[lane]     + w1*gia[64+lane];
            float v2 = w0*gia[128+lane] + w1*gia[192+lane];
#pragma unroll
            for (int off=32; off; off>>=1){ v1 += __shfl_down(v1,off); v2 += __shfl_down(v2,off); }
            if (lane==0){ el[rows[row]] = v1; ers[p0+row] = v2; }
        }
    }
}

// ---------------------------------------------------------------------------
// GAT intra + fused T=1 lg GRU. One wave per SORTED row p.
// ---------------------------------------------------------------------------
__global__ __launch_bounds__(256) void gat_intra_lg(
    const f16* __restrict__ Whs, const float* __restrict__ ers,
    const float* __restrict__ el, const int* __restrict__ sec,
    const int* __restrict__ cnt, const int* __restrict__ base,
    const int* __restrict__ memflat,
    const f16* __restrict__ ggW16,
    const float* __restrict__ ggbih, const float* __restrict__ ggbhh,
    f16* __restrict__ lgout, f16* __restrict__ lgs, int S)
{
    __shared__ __align__(16) f16 irow[4][136];
    int wave = threadIdx.x>>6, lane = threadIdx.x&63;
    int p = blockIdx.x*4 + wave;
    if (p>=S) return;
    int i = memflat[p];
    int g = sec[i];
    int n = cnt[g], b = base[g];
    float eli = el[i];
    float m = -INFINITY;
    for (int jj=lane; jj<n; jj+=64){
        float v = eli + ers[b+jj]; v = v>0.f? v : LRELU_A*v;
        m = fmaxf(m, v);
    }
#pragma unroll
    for (int off=32; off; off>>=1) m = fmaxf(m, __shfl_xor(m, off));
    float l = 0.f, c0=0.f, c1=0.f;
#pragma unroll 4
    for (int jj=0; jj<n; jj++){
        float v = eli + ers[b+jj]; v = v>0.f? v : LRELU_A*v;
        float pw = __expf(v-m);
        l += pw;
        c0 += pw*(float)Whs[(size_t)(b+jj)*128 + lane];
        c1 += pw*(float)Whs[(size_t)(b+jj)*128 + 64 + lane];
    }
    float il = rcpf(l);
    c0 *= il; c1 *= il;
    float e0 = c0>0.f? c0 : expm1f(c0);
    float e1 = c1>0.f? c1 : expm1f(c1);
    irow[wave][lane] = (f16)e0;
    irow[wave][64+lane] = (f16)e1;
    float sr0=0,sr1=0,sz0=0,sz1=0,sn0=0,sn1=0;
    const int j0 = lane, j1 = 64 + lane;
#pragma unroll 4
    for (int kb=0; kb<16; kb++){
        f16x8 hv = *(const f16x8*)&irow[wave][kb*8];
        f16x8 wr0 = *(const f16x8*)&ggW16[(size_t)(j0)*128 + kb*8];
        f16x8 wr1 = *(const f16x8*)&ggW16[(size_t)(j1)*128 + kb*8];
        f16x8 wz0 = *(const f16x8*)&ggW16[(size_t)(128+j0)*128 + kb*8];
        f16x8 wz1 = *(const f16x8*)&ggW16[(size_t)(128+j1)*128 + kb*8];
        f16x8 wn0 = *(const f16x8*)&ggW16[(size_t)(256+j0)*128 + kb*8];
        f16x8 wn1 = *(const f16x8*)&ggW16[(size_t)(256+j1)*128 + kb*8];
#pragma unroll
        for (int e=0;e<8;e++){
            float h = (float)hv[e];
            sr0 = fmaf(h, (float)wr0[e], sr0);
            sr1 = fmaf(h, (float)wr1[e], sr1);
            sz0 = fmaf(h, (float)wz0[e], sz0);
            sz1 = fmaf(h, (float)wz1[e], sz1);
            sn0 = fmaf(h, (float)wn0[e], sn0);
            sn1 = fmaf(h, (float)wn1[e], sn1);
        }
    }
    float r0 = sigm_f(sr0 + ggbih[j0] + ggbhh[j0]);
    float r1 = sigm_f(sr1 + ggbih[j1] + ggbhh[j1]);
    float z0 = sigm_f(sz0 + ggbih[128+j0] + ggbhh[128+j0]);
    float z1 = sigm_f(sz1 + ggbih[128+j1] + ggbhh[128+j1]);
    float n0 = tanh_f(sn0 + ggbih[256+j0] + r0*ggbhh[256+j0]);
    float n1 = tanh_f(sn1 + ggbih[256+j1] + r1*ggbhh[256+j1]);
    f16 v0 = (f16)((1.0f - z0)*n0);
    f16 v1 = (f16)((1.0f - z1)*n1);
    lgout[(size_t)i*128 + j0] = v0;
    lgout[(size_t)i*128 + j1] = v1;
    lgs[(size_t)p*128 + j0] = v0;
    lgs[(size_t)p*128 + j1] = v1;
}

// sector means over SORTED lgs: block g, thread j, contiguous stream
__global__ __launch_bounds__(128) void sector_mean_sorted(
    const f16* __restrict__ lgs, const int* __restrict__ cnt,
    const int* __restrict__ base, float* __restrict__ secf)
{
    int g = blockIdx.x, j = threadIdx.x;
    int n = cnt[g], b = base[g];
    float sum=0.f;
    for (int k=0;k<n;k++) sum += (float)lgs[(size_t)(b+k)*128 + j];
    secf[g*128+j] = sum * rcpf(fmaxf((float)n,1.0f));
}

__global__ __launch_bounds__(256) void gat_inter_kernel(
    const float* __restrict__ secf, const int* __restrict__ adj,
    const float* __restrict__ W, const float* __restrict__ a,
    float* __restrict__ outp)
{
    __shared__ __align__(16) float hsf[16][132];
    __shared__ __align__(16) float Whq[16][132];
    __shared__ float elq[16], erq[16], att[16][16];
    const int tid=threadIdx.x;
    for (int idx=tid; idx<2048; idx+=256){ int s=idx>>7,j=idx&127; hsf[s][j]=secf[idx]; }
    __syncthreads();
#pragma unroll 1
    for (int i=0;i<8;i++){
        int idx=i*256+tid; int o=idx&127, s=idx>>7;
        float a0=0.f,a1=0.f,a2=0.f,a3=0.f;
        for (int j=0;j<128;j+=4){
            a0 += hsf[s][j]  *W[(j  )*128+o];
            a1 += hsf[s][j+1]*W[(j+1)*128+o];
            a2 += hsf[s][j+2]*W[(j+2)*128+o];
            a3 += hsf[s][j+3]*W[(j+3)*128+o];
        }
        Whq[s][o]=(a0+a1)+(a2+a3);
    }
    __syncthreads();
    if (tid<32){
        int s=tid&15; int second = tid>>4;
        const float* av = a + (second?128:0);
        float acc=0.f; for(int o=0;o<128;o++) acc += Whq[s][o]*av[o];
        if (second) erq[s]=acc; else elq[s]=acc;
    }
    __syncthreads();
    if (tid<16){
        int i=tid; float m=NEGBIG; float e[16];
        for(int j=0;j<16;j++){
            float v = elq[i]+erq[j]; v = v>0.f? v : LRELU_A*v;
            e[j] = (adj[i*16+j]>0)? v : NEGBIG;
            m = fmaxf(m,e[j]);
        }
        float l=0.f;
        for(int j=0;j<16;j++){ float p=__expf(e[j]-m); att[i][j]=p; l+=p; }
        float il = rcpf(l);
        for(int j=0;j<16;j++) att[i][j] *= il;
    }
    __syncthreads();
#pragma unroll
    for (int i=0;i<8;i++){
        int idx=i*256+tid; int o=idx&127, s=idx>>7;
        float acc=0.f;
#pragma unroll
        for(int j=0;j<16;j++) acc += att[s][j]*Whq[j][o];
        outp[s*128+o] = acc>0.f? acc : expm1f(acc);
    }
}

// ---------------------------------------------------------------------------
// fused = [lg|la|sec_ps] @ fw + fb, then both heads in-kernel
// ---------------------------------------------------------------------------
__global__ __launch_bounds__(256) void fused_mfma(
    const f16* __restrict__ lg16, const f16* __restrict__ la16,
    const float* __restrict__ seco, const int* __restrict__ sec,
    const f16* __restrict__ fwT,
    const float* __restrict__ fb, const float* __restrict__ rw,
    const float* __restrict__ rb, const float* __restrict__ mw,
    const float* __restrict__ mb, float* __restrict__ outp)
{
    __shared__ float rpart[4][32], mpart[4][32];
    const int tid = threadIdx.x, w = tid>>6, lane = tid&63;
    const int c = lane&15, quad = lane>>4;
    const int s0 = blockIdx.x*32;
    f16x8 A[2][12];
#pragma unroll
    for (int mt=0;mt<2;mt++){
        int row = s0 + mt*16 + c;
        int g = sec[row];
#pragma unroll
        for (int kb=0;kb<4;kb++){
            A[mt][kb]   = *(const f16x8*)&lg16[(size_t)row*128 + kb*32 + quad*8];
            A[mt][4+kb] = *(const f16x8*)&la16[(size_t)row*128 + kb*32 + quad*8];
            A[mt][8+kb] = load_cvt8(&seco[(size_t)g*128 + kb*32 + quad*8]);
        }
    }
    float rsum[2][4] = {{0,0,0,0},{0,0,0,0}};
    float msum[2][4] = {{0,0,0,0},{0,0,0,0}};
#pragma unroll
    for (int i=0;i<2;i++){
        int jb = w*2 + i;
        int col = jb*16 + c;
        f16x8 B[12];
#pragma unroll
        for (int kb=0;kb<12;kb++)
            B[kb] = *(const f16x8*)&fwT[(size_t)col*384 + kb*32 + quad*8];
        floatx4 acc[2] = {{0,0,0,0},{0,0,0,0}};
#pragma unroll
        for (int kb=0;kb<12;kb++){
            acc[0] = MFMA16(A[0][kb], B[kb], acc[0]);
            acc[1] = MFMA16(A[1][kb], B[kb], acc[1]);
        }
        float fbv = fb[col], rwv = rw[col], mwv = mw[col];
#pragma unroll
        for (int mt=0;mt<2;mt++)
#pragma unroll
            for (int r=0;r<4;r++){
                float fu = acc[mt][r] + fbv;
                rsum[mt][r] += fu*rwv;
                msum[mt][r] += fu*mwv;
            }
    }
#pragma unroll
    for (int mt=0;mt<2;mt++)
#pragma unroll
        for (int r=0;r<4;r++){
#pragma unroll
            for (int off=1; off<16; off<<=1){
                rsum[mt][r] += __shfl_xor(rsum[mt][r], off);
                msum[mt][r] += __shfl_xor(msum[mt][r], off);
            }
            if (c==0){
                rpart[w][mt*16 + quad*4 + r] = rsum[mt][r];
                mpart[w][mt*16 + quad*4 + r] = msum[mt][r];
            }
        }
    __syncthreads();
    if (tid < 32){
        int s = tid;
        float rs = rb[0], ms = mb[0];
#pragma unroll
        for (int ww=0; ww<4; ww++){ rs += rpart[ww][s]; ms += mpart[ww][s]; }
        outp[s0+s] = rs;
        outp[2048 + s0 + s] = sigm(ms);
    }
}

extern "C" void kernel_launch(void* const* d_in, const int* in_sizes, int n_in,
                              void* d_out, int out_size, void* d_ws, size_t ws_size,
                              hipStream_t stream) {
    const float* sf    = (const float*)d_in[0];
    const int*   sec   = (const int*)  d_in[1];
    const int*   adj   = (const int*)  d_in[2];
    const float* g1Wih = (const float*)d_in[3];
    const float* g1Whh = (const float*)d_in[4];
    const float* g1bih = (const float*)d_in[5];
    const float* g1bhh = (const float*)d_in[6];
    const float* a1w   = (const float*)d_in[7];
    const float* a1b   = (const float*)d_in[8];
    const float* giW   = (const float*)d_in[9];
    const float* gia   = (const float*)d_in[10];
    const float* ggWih = (const float*)d_in[11];
    const float* ggbih = (const float*)d_in[13];
    const float* ggbhh = (const float*)d_in[14];
    const float* gaWih = (const float*)d_in[17];
    const float* gaWhh = (const float*)d_in[18];
    const float* gabih = (const float*)d_in[19];
    const float* gabhh = (const float*)d_in[20];
    const float* aaw   = (const float*)d_in[21];
    const float* aab   = (const float*)d_in[22];
    const float* geW   = (const float*)d_in[23];
    const float* gea   = (const float*)d_in[24];
    const float* fw    = (const float*)d_in[25];
    const float* fb    = (const float*)d_in[26];
    const float* rw    = (const float*)d_in[27];
    const float* rb    = (const float*)d_in[28];
    const float* mw    = (const float*)d_in[29];
    const float* mb    = (const float*)d_in[30];

    char* p = (char*)d_ws;
    f16*   shrt16 = (f16*)p;   p += (size_t)65536*128*2;
    f16*   lg16   = (f16*)p;   p += (size_t)262144*2;
    f16*   lgs    = (f16*)p;   p += (size_t)262144*2;
    f16*   la16   = (f16*)p;   p += (size_t)262144*2;
    f16*   Whs    = (f16*)p;   p += (size_t)262144*2;
    f16*   Wcat1  = (f16*)p;   p += (size_t)512*160*2;
    f16*   WcatA  = (f16*)p;   p += (size_t)512*256*2;
    f16*   WT     = (f16*)p;   p += (size_t)16384*2;
    f16*   fwT    = (f16*)p;   p += (size_t)49152*2;
    f16*   ggW16  = (f16*)p;   p += (size_t)49152*2;
    float* el     = (float*)p; p += 2048*4;
    float* ers    = (float*)p; p += 2048*4;
    float* secf   = (float*)p; p += 2048*4;
    float* seco   = (float*)p; p += 2048*4;
    int*   memflat= (int*)p;   p += 2048*4;
    int*   cnt    = (int*)p;   p += 16*4;
    int*   basep  = (int*)p;   p += 16*4;

    // 0. weight prep + bucketing
    prep_kernel<<<865,256,0,stream>>>(g1Wih, g1Whh, gaWih, gaWhh, giW, fw, ggWih, sec,
                                      Wcat1, WcatA, WT, fwT, ggW16, memflat, cnt, basep);
    // 1. short GRU+attn (65536 windows, T=5), M=64/block
    gru_short<<<1024,512,0,stream>>>(sf, Wcat1, g1bih, g1bhh, a1w, a1b, shrt16);
    // 2. la GRU+attn + gat_prep merged
    la_gatprep<<<320,512,0,stream>>>(shrt16, WcatA, gabih, gabhh, aaw, aab, la16,
                                     WT, gia, memflat, Whs, ers, el);
    // 3. intra-sector GAT + lg (T=1 GRU), sorted-order rows
    gat_intra_lg<<<512,256,0,stream>>>(Whs, ers, el, sec, cnt, basep, memflat,
                                       ggW16, ggbih, ggbhh, lg16, lgs, 2048);
    // 4a. sector means over sorted lgs (16 CUs, coalesced)
    sector_mean_sorted<<<16,128,0,stream>>>(lgs, cnt, basep, secf);
    // 4b. inter-sector GAT (tiny)
    gat_inter_kernel<<<1,256,0,stream>>>(secf, adj, geW, gea, seco);
    // 5. fusion + heads
    fused_mfma<<<64,256,0,stream>>>(lg16, la16, seco, sec, fwT, fb, rw, rb, mw, mb, (float*)d_out);
}

// Round 11
// 356.214 us; speedup vs baseline: 1.8421x; 1.0869x over previous
//
#include <hip/hip_runtime.h>
#include <math.h>

#define LRELU_A 0.2f
#define NEGBIG (-9.0e15f)

typedef _Float16 f16;
typedef _Float16 f16x8 __attribute__((ext_vector_type(8)));
typedef _Float16 f16x4 __attribute__((ext_vector_type(4)));
typedef float floatx4 __attribute__((ext_vector_type(4)));

__device__ __forceinline__ float rcpf(float x){ return __builtin_amdgcn_rcpf(x); }
__device__ __forceinline__ float sigm_f(float x){ return rcpf(1.0f + __expf(-x)); }
__device__ __forceinline__ float tanh_f(float x){ return 1.0f - 2.0f*rcpf(1.0f + __expf(2.0f*x)); }
__device__ __forceinline__ float sigm(float x){ return rcpf(1.0f+__expf(-x)); }
__device__ __forceinline__ f16x8 load_cvt8(const float* __restrict__ p){
    float4 a = *(const float4*)p; float4 b = *(const float4*)(p+4);
    f16x8 r; r[0]=(f16)a.x; r[1]=(f16)a.y; r[2]=(f16)a.z; r[3]=(f16)a.w;
    r[4]=(f16)b.x; r[5]=(f16)b.y; r[6]=(f16)b.z; r[7]=(f16)b.w;
    return r;
}
#define MFMA16(A,B,C) __builtin_amdgcn_mfma_f32_16x16x32_f16((A),(B),(C),0,0,0)

// ---------------------------------------------------------------------------
// prep: Wcat1 | WcatA | WT | fwT | ggW16 | bucket. 865 blocks.
// ---------------------------------------------------------------------------
__global__ __launch_bounds__(256) void prep_kernel(
    const float* __restrict__ g1Wih, const float* __restrict__ g1Whh,
    const float* __restrict__ gaWih, const float* __restrict__ gaWhh,
    const float* __restrict__ giW,   const float* __restrict__ fw,
    const float* __restrict__ ggWih, const int* __restrict__ sec,
    f16* __restrict__ Wcat1, f16* __restrict__ WcatA,
    f16* __restrict__ WT, f16* __restrict__ fwT, f16* __restrict__ ggW16,
    int* __restrict__ memflat, int* __restrict__ cnt, int* __restrict__ base)
{
    __shared__ int cs[16], wsc[16];
    const int b = blockIdx.x, tid = threadIdx.x;
    if (b < 160){                      // Wcat1: INF=16, INFPAD=32, KTOT=160
        for (int idx = b*256+tid; idx < 512*160; idx += 160*256){
            int r = idx/160, k = idx - r*160;
            float v = 0.0f;
            if (r < 256){ if (k < 32){ if (k < 16) v = g1Wih[r*16+k]; } else v = g1Whh[r*128 + (k-32)]; }
            else if (r < 384){ if (k < 16) v = g1Wih[r*16+k]; }
            else { if (k >= 32) v = g1Whh[(r-128)*128 + (k-32)]; }
            Wcat1[idx] = (f16)v;
        }
    } else if (b < 416){               // WcatA: INF=128, KTOT=256
        for (int idx = (b-160)*256+tid; idx < 512*256; idx += 256*256){
            int r = idx >> 8, k = idx & 255;
            float v = 0.0f;
            if (r < 256){ v = (k < 128) ? gaWih[r*128+k] : gaWhh[r*128 + (k-128)]; }
            else if (r < 384){ if (k < 128) v = gaWih[r*128+k]; }
            else { if (k >= 128) v = gaWhh[(r-128)*128 + (k-128)]; }
            WcatA[idx] = (f16)v;
        }
    } else if (b < 480){               // WT = giW^T (128x128)
        int idx = (b-416)*256+tid;
        int r = idx >> 7, c = idx & 127;
        WT[c*128 + r] = (f16)giW[idx];
    } else if (b < 672){               // fwT = fw^T (384x128 -> 128x384)
        int idx = (b-480)*256+tid;
        int r = idx >> 7, c = idx & 127;
        fwT[c*384 + r] = (f16)fw[idx];
    } else if (b < 864){               // ggW16 = (f16)ggWih  [384][128]
        int idx = (b-672)*256+tid;
        ggW16[idx] = (f16)ggWih[idx];
    } else {                           // bucket
        if (tid < 16) cs[tid] = 0;
        __syncthreads();
        for (int s = tid; s < 2048; s += 256) atomicAdd(&cs[sec[s]], 1);
        __syncthreads();
        if (tid == 0){
            int acc = 0;
            for (int g=0; g<16; g++){ cnt[g]=cs[g]; base[g]=acc; wsc[g]=acc; acc+=cs[g]; }
        }
        __syncthreads();
        for (int s = tid; s < 2048; s += 256){
            int g = sec[s];
            int p = atomicAdd(&wsc[g], 1);
            memflat[p] = s;
        }
    }
}

// ---------------------------------------------------------------------------
// Short GRU+attn v6. M=64 seqs/block, 1024 blocks, 8 waves.
// xs double-buffered (LDS exactly 48KB -> 3 blocks/CU vs 64.5KB -> 2),
// per-step register prefetch of x_{t+1}. Lagged unnormalized softmax,
// 1 barrier/step. R8: big M amortizes. R9: staged beats direct Bx.
// NOTE (512,2): (512,4) caps VGPR at 64 -> massive spill (R5).
// ---------------------------------------------------------------------------
__global__ __launch_bounds__(512,2) void gru_short(
    const float* __restrict__ x, const f16* __restrict__ Wcat,
    const float* __restrict__ bih, const float* __restrict__ bhh,
    const float* __restrict__ aw, const float* __restrict__ ab,
    f16* __restrict__ out)
{
    __shared__ __align__(16) f16 xs[2][64][40];     // cols 16..39 zero
    __shared__ __align__(16) f16 hs[2][64][136];
    __shared__ float scpart[2][8][64];
    const int tid = threadIdx.x, w = tid>>6, lane = tid&63;
    const int c = lane&15, quad = lane>>4;
    const int s0 = blockIdx.x*64;

    { f16x4 z4 = {0,0,0,0};
      f16x4* zx = (f16x4*)&xs[0][0][0];
      for (int i=tid; i<1280; i+=512) zx[i] = z4;
      f16x4* zh = (f16x4*)&hs[1][0][0];
      for (int i=tid; i<2176; i+=512) zh[i] = z4; }
    // stage x_0 into xs[0]
    if (tid < 256){
        int s = tid>>2, q = tid&3;
        float4 v = *(const float4*)&x[(size_t)(s0+s)*80 + q*4];
        f16x4 h4; h4[0]=(f16)v.x; h4[1]=(f16)v.y; h4[2]=(f16)v.z; h4[3]=(f16)v.w;
        *(f16x4*)&xs[0][s][q*4] = h4;
    }
    const int jrow = w*16 + c;
    f16x8 Ar[5], Az[5], Agi, Agh[4];
#pragma unroll
    for (int kb=0;kb<5;kb++){
        Ar[kb] = *(const f16x8*)&Wcat[(size_t)(jrow)*160 + kb*32 + quad*8];
        Az[kb] = *(const f16x8*)&Wcat[(size_t)(128+jrow)*160 + kb*32 + quad*8];
    }
    Agi = *(const f16x8*)&Wcat[(size_t)(256+jrow)*160 + quad*8];
#pragma unroll
    for (int i=0;i<4;i++)
        Agh[i] = *(const f16x8*)&Wcat[(size_t)(384+jrow)*160 + 32 + i*32 + quad*8];

    float brz_r[4], brz_z[4], b_in[4], b_hn[4], awr[4];
#pragma unroll
    for (int r=0;r<4;r++){
        int j = w*16 + quad*4 + r;
        brz_r[r] = bih[j] + bhh[j];
        brz_z[r] = bih[128+j] + bhh[128+j];
        b_in[r] = bih[256+j]; b_hn[r] = bhh[256+j];
        awr[r] = aw[j];
    }
    const float abv = ab[0];
    float hreg[4][4], aacc[4][4], l_[4] = {0.0f,0.0f,0.0f,0.0f};
#pragma unroll
    for (int st=0; st<4; st++)
#pragma unroll
        for (int r=0;r<4;r++){ hreg[st][r]=0.0f; aacc[st][r]=0.0f; }
    __syncthreads();

#pragma unroll 1
    for (int t=0; t<5; ++t){
        const int rp = (t&1)^1, wp = t&1, xp = t&1;
        // prefetch x_{t+1} to regs (written to xs[xp^1] before the barrier)
        float4 xv;
        const bool st_ok = (t < 4) && (tid < 256);
        if (st_ok)
            xv = *(const float4*)&x[(size_t)(s0+(tid>>2))*80 + (t+1)*16 + (tid&3)*4];
        // lagged attention: apply step t-1's weight to h_{t-1}
        if (t > 0){
#pragma unroll
            for (int st=0; st<4; st++){
                float sc = abv;
#pragma unroll
                for (int ww=0; ww<8; ww++) sc += scpart[rp][ww][st*16+c];
                float e = __expf(sc);
                l_[st] += e;
#pragma unroll
                for (int r=0;r<4;r++) aacc[st][r] += e*hreg[st][r];
            }
        }
        float sp[4];
#pragma unroll
        for (int st=0; st<4; st++){
            f16x8 Bx = *(const f16x8*)&xs[xp][st*16+c][quad*8];
            f16x8 Bh[4];
#pragma unroll
            for (int i=0;i<4;i++)
                Bh[i] = *(const f16x8*)&hs[rp][st*16+c][i*32+quad*8];
            floatx4 ar = {0,0,0,0}, az = {0,0,0,0}, agi = {0,0,0,0}, agh = {0,0,0,0};
            ar = MFMA16(Ar[0], Bx, ar);
            az = MFMA16(Az[0], Bx, az);
            agi = MFMA16(Agi, Bx, agi);
#pragma unroll
            for (int i=0;i<4;i++){
                ar = MFMA16(Ar[1+i], Bh[i], ar);
                az = MFMA16(Az[1+i], Bh[i], az);
                agh = MFMA16(Agh[i], Bh[i], agh);
            }
            f16x4 h4;
            sp[st] = 0.0f;
#pragma unroll
            for (int r=0;r<4;r++){
                float rg = sigm_f(ar[r] + brz_r[r]);
                float zg = sigm_f(az[r] + brz_z[r]);
                float ng = tanh_f(agi[r] + b_in[r] + rg*(agh[r] + b_hn[r]));
                float hn = fmaf(zg, hreg[st][r] - ng, ng);
                hreg[st][r] = hn; h4[r] = (f16)hn;
                sp[st] += hn * awr[r];
            }
            *(f16x4*)&hs[wp][st*16 + c][w*16 + quad*4] = h4;
        }
        if (st_ok){
            f16x4 h4; h4[0]=(f16)xv.x; h4[1]=(f16)xv.y; h4[2]=(f16)xv.z; h4[3]=(f16)xv.w;
            *(f16x4*)&xs[xp^1][tid>>2][(tid&3)*4] = h4;
        }
#pragma unroll
        for (int st=0; st<4; st++){
            sp[st] += __shfl_xor(sp[st], 16);
            sp[st] += __shfl_xor(sp[st], 32);
        }
        if (lane < 16){
#pragma unroll
            for (int st=0; st<4; st++) scpart[wp][w][st*16+lane] = sp[st];
        }
        __syncthreads();
    }
    // drain (t=4 wrote scpart[0] and hs[0])
#pragma unroll
    for (int st=0; st<4; st++){
        float sc = abv;
#pragma unroll
        for (int ww=0; ww<8; ww++) sc += scpart[0][ww][st*16+c];
        float e = __expf(sc);
        l_[st] += e;
        float inv = rcpf(l_[st]);
        f16x4 h4;
#pragma unroll
        for (int r=0;r<4;r++) h4[r] = (f16)((aacc[st][r] + e*hreg[st][r])*inv);
        *(f16x4*)&hs[0][st*16 + c][w*16 + quad*4] = h4;
    }
    __syncthreads();
    for (int i=tid; i<1024; i+=512){
        int s = i>>4, p = i&15;
        *(f16x8*)&out[(size_t)(s0+s)*128 + p*8] = *(const f16x8*)&hs[0][s][p*8];
    }
}

// ---------------------------------------------------------------------------
// Merged: blocks 0..255 -> la GRU+attn (M=8 real); 256..319 -> gat_prep.
// ---------------------------------------------------------------------------
__global__ __launch_bounds__(512,2) void la_gatprep(
    const f16* __restrict__ shrt16, const f16* __restrict__ Wcat,
    const float* __restrict__ bih, const float* __restrict__ bhh,
    const float* __restrict__ aw, const float* __restrict__ ab,
    f16* __restrict__ la16,
    const f16* __restrict__ WT, const float* __restrict__ gia,
    const int* __restrict__ memflat,
    f16* __restrict__ Whs, float* __restrict__ ers, float* __restrict__ el)
{
    __shared__ __align__(16) char smem[17152];
    const int tid = threadIdx.x, w = tid>>6, lane = tid&63;
    const int c = lane&15, quad = lane>>4;

    if (blockIdx.x < 256){
        // ---------------- la GRU ----------------
        f16* hsp = (f16*)smem;                        // [2][16][136]
        float* scp = (float*)(smem + 2*16*136*2);     // [2][8][16]
        const int s0 = blockIdx.x*8;
        const int sx = (s0 + c < 2047) ? (s0 + c) : 2047;

        { f16x4 z4 = {0,0,0,0};
          f16x4* zh = (f16x4*)(hsp + 16*136);
          for (int i=tid; i<544; i+=512) zh[i] = z4; }

        const int jrow = w*16 + c;
        f16x8 Ar[8], Az[8], Agi[4], Agh[4];
#pragma unroll
        for (int kb=0;kb<8;kb++){
            Ar[kb] = *(const f16x8*)&Wcat[(size_t)(jrow)*256 + kb*32 + quad*8];
            Az[kb] = *(const f16x8*)&Wcat[(size_t)(128+jrow)*256 + kb*32 + quad*8];
        }
#pragma unroll
        for (int i=0;i<4;i++){
            Agi[i] = *(const f16x8*)&Wcat[(size_t)(256+jrow)*256 + i*32 + quad*8];
            Agh[i] = *(const f16x8*)&Wcat[(size_t)(384+jrow)*256 + 128 + i*32 + quad*8];
        }
        float brz_r[4], brz_z[4], b_in[4], b_hn[4], awr[4];
#pragma unroll
        for (int r=0;r<4;r++){
            int j = w*16 + quad*4 + r;
            brz_r[r] = bih[j] + bhh[j];
            brz_z[r] = bih[128+j] + bhh[128+j];
            b_in[r] = bih[256+j]; b_hn[r] = bhh[256+j];
            awr[r] = aw[j];
        }
        const float abv = ab[0];
        float hreg[4] = {0,0,0,0}, aacc[4] = {0,0,0,0}, l_ = 0.0f;
        f16x8 Bxc[4];
#pragma unroll
        for (int i=0;i<4;i++)
            Bxc[i] = *(const f16x8*)&shrt16[((size_t)sx*32 + 0)*128 + i*32 + quad*8];
        __syncthreads();

#pragma unroll 1
        for (int t=0; t<32; ++t){
            const int rp = (t&1)^1, wp = t&1;
            f16x8 Bh[4];
#pragma unroll
            for (int i=0;i<4;i++)
                Bh[i] = *(const f16x8*)&hsp[((size_t)rp*16 + c)*136 + i*32 + quad*8];
            f16x8 Bxn[4];
            if (t < 31){
#pragma unroll
                for (int i=0;i<4;i++)
                    Bxn[i] = *(const f16x8*)&shrt16[((size_t)sx*32 + t+1)*128 + i*32 + quad*8];
            }
            if (t > 0){
                float sc = abv;
#pragma unroll
                for (int ww=0; ww<8; ww++) sc += scp[(rp*8+ww)*16 + c];
                float e = __expf(sc);
                l_ += e;
#pragma unroll
                for (int r=0;r<4;r++) aacc[r] += e*hreg[r];
            }
            floatx4 ar = {0,0,0,0}, az = {0,0,0,0}, agi = {0,0,0,0}, agh = {0,0,0,0};
#pragma unroll
            for (int i=0;i<4;i++){
                ar = MFMA16(Ar[i], Bxc[i], ar);
                az = MFMA16(Az[i], Bxc[i], az);
                agi = MFMA16(Agi[i], Bxc[i], agi);
            }
#pragma unroll
            for (int i=0;i<4;i++){
                ar = MFMA16(Ar[4+i], Bh[i], ar);
                az = MFMA16(Az[4+i], Bh[i], az);
                agh = MFMA16(Agh[i], Bh[i], agh);
            }
            f16x4 h4;
            float sp = 0.0f;
#pragma unroll
            for (int r=0;r<4;r++){
                float rg = sigm_f(ar[r] + brz_r[r]);
                float zg = sigm_f(az[r] + brz_z[r]);
                float ng = tanh_f(agi[r] + b_in[r] + rg*(agh[r] + b_hn[r]));
                float hn = fmaf(zg, hreg[r] - ng, ng);
                hreg[r] = hn; h4[r] = (f16)hn;
                sp += hn * awr[r];
            }
            *(f16x4*)&hsp[((size_t)wp*16 + c)*136 + w*16 + quad*4] = h4;
            sp += __shfl_xor(sp, 16);
            sp += __shfl_xor(sp, 32);
            if (lane < 16) scp[(wp*8+w)*16 + lane] = sp;
#pragma unroll
            for (int i=0;i<4;i++) Bxc[i] = Bxn[i];
            __syncthreads();
        }
        // drain (t=31 wrote parity 1)
        {
            float sc = abv;
#pragma unroll
            for (int ww=0; ww<8; ww++) sc += scp[(8+ww)*16 + c];
            float e = __expf(sc);
            l_ += e;
            float inv = rcpf(l_);
            f16x4 h4;
#pragma unroll
            for (int r=0;r<4;r++) h4[r] = (f16)((aacc[r] + e*hreg[r])*inv);
            *(f16x4*)&hsp[((size_t)16 + c)*136 + w*16 + quad*4] = h4;
        }
        __syncthreads();
        if (tid < 128){
            int s = tid>>4, p = tid&15;
            *(f16x8*)&la16[(size_t)(s0+s)*128 + p*8] =
                *(const f16x8*)&hsp[((size_t)16 + s)*136 + p*8];
        }
    } else {
        // ---------------- gat_prep (512-thread variant) ----------------
        float* tbuf = (float*)smem;                   // [32][132]
        int* rows = (int*)(smem + 32*132*4);
        const int p0 = (blockIdx.x - 256)*32;
        if (tid < 32) rows[tid] = memflat[p0 + tid];
        __syncthreads();
        f16x8 A[2][4];
#pragma unroll
        for (int mt=0;mt<2;mt++)
#pragma unroll
            for (int kb=0;kb<4;kb++)
                A[mt][kb] = *(const f16x8*)&shrt16[((size_t)rows[mt*16+c]*32 + 31)*128 + kb*32 + quad*8];
        const int jb = w;
        f16x8 B[4];
#pragma unroll
        for (int kb=0;kb<4;kb++)
            B[kb] = *(const f16x8*)&WT[(size_t)(jb*16+c)*128 + kb*32 + quad*8];
        floatx4 acc[2] = {{0,0,0,0},{0,0,0,0}};
#pragma unroll
        for (int kb=0;kb<4;kb++){
            acc[0] = MFMA16(A[0][kb], B[kb], acc[0]);
            acc[1] = MFMA16(A[1][kb], B[kb], acc[1]);
        }
#pragma unroll
        for (int mt=0;mt<2;mt++)
#pragma unroll
            for (int r=0;r<4;r++)
                tbuf[(mt*16 + quad*4 + r)*132 + jb*16 + c] = acc[mt][r];
        __syncthreads();
        for (int i=tid; i<1024; i+=512){
            int s = i>>5, p = i&31;
            float4 v = *(const float4*)&tbuf[s*132 + p*4];
            f16x4 h4; h4[0]=(f16)v.x; h4[1]=(f16)v.y; h4[2]=(f16)v.z; h4[3]=(f16)v.w;
            *(f16x4*)&Whs[(size_t)(p0+s)*128 + p*4] = h4;
        }
#pragma unroll
        for (int k=0; k<4; k++){
            int row = w*4 + k;
            float w0 = tbuf[row*132 + lane], w1 = tbuf[row*132 + 64 + lane];
            float v1 = w0*gia[lane]     + w1*gia[64+lane];
            float v2 = w0*gia[128+lane] + w1*gia[192+lane];
#pragma unroll
            for (int off=32; off; off>>=1){ v1 += __shfl_down(v1,off); v2 += __shfl_down(v2,off); }
            if (lane==0){ el[rows[row]] = v1; ers[p0+row] = v2; }
        }
    }
}

// ---------------------------------------------------------------------------
// GAT intra, member-list, SORTED rows. One wave per sorted row p.
// Writes intra_s (sorted order) — consumed by lg_mfma_sorted.
// ---------------------------------------------------------------------------
__global__ __launch_bounds__(256) void gat_intra_mem_kernel(
    const f16* __restrict__ Whs, const float* __restrict__ ers,
    const float* __restrict__ el, const int* __restrict__ sec,
    const int* __restrict__ cnt, const int* __restrict__ base,
    const int* __restrict__ memflat,
    f16* __restrict__ intra_s, int S)
{
    int wave = threadIdx.x>>6, lane = threadIdx.x&63;
    int p = blockIdx.x*4 + wave;
    if (p>=S) return;
    int i = memflat[p];
    int g = sec[i];
    int n = cnt[g], b = base[g];
    float eli = el[i];
    float m = -INFINITY;
    for (int jj=lane; jj<n; jj+=64){
        float v = eli + ers[b+jj]; v = v>0.f? v : LRELU_A*v;
        m = fmaxf(m, v);
    }
#pragma unroll
    for (int off=32; off; off>>=1) m = fmaxf(m, __shfl_xor(m, off));
    float l = 0.f, c0=0.f, c1=0.f;
#pragma unroll 4
    for (int jj=0; jj<n; jj++){
        float v = eli + ers[b+jj]; v = v>0.f? v : LRELU_A*v;
        float pw = __expf(v-m);
        l += pw;
        c0 += pw*(float)Whs[(size_t)(b+jj)*128 + lane];
        c1 += pw*(float)Whs[(size_t)(b+jj)*128 + 64 + lane];
    }
    float il = rcpf(l);
    c0 *= il; c1 *= il;
    intra_s[(size_t)p*128 + lane]      = (f16)(c0>0.f? c0 : expm1f(c0));
    intra_s[(size_t)p*128 + 64 + lane] = (f16)(c1>0.f? c1 : expm1f(c1));
}

// ---------------------------------------------------------------------------
// lg: T=1 GRU via MFMA over SORTED intra rows. Writes lg_s (sorted) and
// lg16 (orig order, scattered via memflat).
// ---------------------------------------------------------------------------
__global__ __launch_bounds__(256) void lg_mfma_sorted(
    const f16* __restrict__ intra_s, const f16* __restrict__ ggW16,
    const float* __restrict__ bih, const float* __restrict__ bhh,
    const int* __restrict__ memflat,
    f16* __restrict__ lg16, f16* __restrict__ lg_s)
{
    __shared__ __align__(16) f16 tbuf[32][136];
    __shared__ int rows[32];
    const int tid = threadIdx.x, w = tid>>6, lane = tid&63;
    const int c = lane&15, quad = lane>>4;
    const int p0 = blockIdx.x*32;
    if (tid < 32) rows[tid] = memflat[p0 + tid];
    f16x8 A[2][4];
#pragma unroll
    for (int mt=0;mt<2;mt++)
#pragma unroll
        for (int kb=0;kb<4;kb++)
            A[mt][kb] = *(const f16x8*)&intra_s[(size_t)(p0+mt*16+c)*128 + kb*32 + quad*8];
#pragma unroll
    for (int i=0;i<2;i++){
        int jb = w*2 + i;
        int j = jb*16 + c;
        f16x8 Br[4], Bz[4], Bn[4];
#pragma unroll
        for (int kb=0;kb<4;kb++){
            Br[kb] = *(const f16x8*)&ggW16[(size_t)(j)*128 + kb*32 + quad*8];
            Bz[kb] = *(const f16x8*)&ggW16[(size_t)(128+j)*128 + kb*32 + quad*8];
            Bn[kb] = *(const f16x8*)&ggW16[(size_t)(256+j)*128 + kb*32 + quad*8];
        }
        float b_r = bih[j] + bhh[j];
        float b_z = bih[128+j] + bhh[128+j];
        float b_i = bih[256+j], b_h = bhh[256+j];
        floatx4 ar[2] = {{0,0,0,0},{0,0,0,0}};
        floatx4 az[2] = {{0,0,0,0},{0,0,0,0}};
        floatx4 an[2] = {{0,0,0,0},{0,0,0,0}};
#pragma unroll
        for (int kb=0;kb<4;kb++)
#pragma unroll
            for (int mt=0;mt<2;mt++){
                ar[mt] = MFMA16(A[mt][kb], Br[kb], ar[mt]);
                az[mt] = MFMA16(A[mt][kb], Bz[kb], az[mt]);
                an[mt] = MFMA16(A[mt][kb], Bn[kb], an[mt]);
            }
#pragma unroll
        for (int mt=0;mt<2;mt++)
#pragma unroll
            for (int r=0;r<4;r++){
                float rg = sigm_f(ar[mt][r] + b_r);
                float zg = sigm_f(az[mt][r] + b_z);
                float ng = tanh_f(an[mt][r] + b_i + rg*b_h);
                tbuf[mt*16 + quad*4 + r][j] = (f16)((1.0f - zg)*ng);
            }
    }
    __syncthreads();
    for (int i=tid; i<512; i+=256){
        int s = i>>4, p = i&15;
        f16x8 v = *(const f16x8*)&tbuf[s][p*8];
        *(f16x8*)&lg_s[(size_t)(p0+s)*128 + p*8] = v;
        *(f16x8*)&lg16[(size_t)rows[s]*128 + p*8] = v;
    }
}

// sector means over SORTED lg_s: block g, thread j, contiguous stream
__global__ __launch_bounds__(128) void sector_mean_sorted(
    const f16* __restrict__ lgs, const int* __restrict__ cnt,
    const int* __restrict__ base, float* __restrict__ secf)
{
    int g = blockIdx.x, j = threadIdx.x;
    int n = cnt[g], b = base[g];
    float sum=0.f;
    for (int k=0;k<n;k++) sum += (float)lgs[(size_t)(b+k)*128 + j];
    secf[g*128+j] = sum * rcpf(fmaxf((float)n,1.0f));
}

__global__ __launch_bounds__(256) void gat_inter_kernel(
    const float* __restrict__ secf, const int* __restrict__ adj,
    const float* __restrict__ W, const float* __restrict__ a,
    float* __restrict__ outp)
{
    __shared__ __align__(16) float hsf[16][132];
    __shared__ __align__(16) float Whq[16][132];
    __shared__ float elq[16], erq[16], att[16][16];
    const int tid=threadIdx.x;
    for (int idx=tid; idx<2048; idx+=256){ int s=idx>>7,j=idx&127; hsf[s][j]=secf[idx]; }
    __syncthreads();
#pragma unroll 1
    for (int i=0;i<8;i++){
        int idx=i*256+tid; int o=idx&127, s=idx>>7;
        float a0=0.f,a1=0.f,a2=0.f,a3=0.f;
        for (int j=0;j<128;j+=4){
            a0 += hsf[s][j]  *W[(j  )*128+o];
            a1 += hsf[s][j+1]*W[(j+1)*128+o];
            a2 += hsf[s][j+2]*W[(j+2)*128+o];
            a3 += hsf[s][j+3]*W[(j+3)*128+o];
        }
        Whq[s][o]=(a0+a1)+(a2+a3);
    }
    __syncthreads();
    if (tid<32){
        int s=tid&15; int second = tid>>4;
        const float* av = a + (second?128:0);
        float acc=0.f; for(int o=0;o<128;o++) acc += Whq[s][o]*av[o];
        if (second) erq[s]=acc; else elq[s]=acc;
    }
    __syncthreads();
    if (tid<16){
        int i=tid; float m=NEGBIG; float e[16];
        for(int j=0;j<16;j++){
            float v = elq[i]+erq[j]; v = v>0.f? v : LRELU_A*v;
            e[j] = (adj[i*16+j]>0)? v : NEGBIG;
            m = fmaxf(m,e[j]);
        }
        float l=0.f;
        for(int j=0;j<16;j++){ float p=__expf(e[j]-m); att[i][j]=p; l+=p; }
        float il = rcpf(l);
        for(int j=0;j<16;j++) att[i][j] *= il;
    }
    __syncthreads();
#pragma unroll
    for (int i=0;i<8;i++){
        int idx=i*256+tid; int o=idx&127, s=idx>>7;
        float acc=0.f;
#pragma unroll
        for(int j=0;j<16;j++) acc += att[s][j]*Whq[j][o];
        outp[s*128+o] = acc>0.f? acc : expm1f(acc);
    }
}

// ---------------------------------------------------------------------------
// fused = [lg|la|sec_ps] @ fw + fb, then both heads in-kernel
// ---------------------------------------------------------------------------
__global__ __launch_bounds__(256) void fused_mfma(
    const f16* __restrict__ lg16, const f16* __restrict__ la16,
    const float* __restrict__ seco, const int* __restrict__ sec,
    const f16* __restrict__ fwT,
    const float* __restrict__ fb, const float* __restrict__ rw,
    const float* __restrict__ rb, const float* __restrict__ mw,
    const float* __restrict__ mb, float* __restrict__ outp)
{
    __shared__ float rpart[4][32], mpart[4][32];
    const int tid = threadIdx.x, w = tid>>6, lane = tid&63;
    const int c = lane&15, quad = lane>>4;
    const int s0 = blockIdx.x*32;
    f16x8 A[2][12];
#pragma unroll
    for (int mt=0;mt<2;mt++){
        int row = s0 + mt*16 + c;
        int g = sec[row];
#pragma unroll
        for (int kb=0;kb<4;kb++){
            A[mt][kb]   = *(const f16x8*)&lg16[(size_t)row*128 + kb*32 + quad*8];
            A[mt][4+kb] = *(const f16x8*)&la16[(size_t)row*128 + kb*32 + quad*8];
            A[mt][8+kb] = load_cvt8(&seco[(size_t)g*128 + kb*32 + quad*8]);
        }
    }
    float rsum[2][4] = {{0,0,0,0},{0,0,0,0}};
    float msum[2][4] = {{0,0,0,0},{0,0,0,0}};
#pragma unroll
    for (int i=0;i<2;i++){
        int jb = w*2 + i;
        int col = jb*16 + c;
        f16x8 B[12];
#pragma unroll
        for (int kb=0;kb<12;kb++)
            B[kb] = *(const f16x8*)&fwT[(size_t)col*384 + kb*32 + quad*8];
        floatx4 acc[2] = {{0,0,0,0},{0,0,0,0}};
#pragma unroll
        for (int kb=0;kb<12;kb++){
            acc[0] = MFMA16(A[0][kb], B[kb], acc[0]);
            acc[1] = MFMA16(A[1][kb], B[kb], acc[1]);
        }
        float fbv = fb[col], rwv = rw[col], mwv = mw[col];
#pragma unroll
        for (int mt=0;mt<2;mt++)
#pragma unroll
            for (int r=0;r<4;r++){
                float fu = acc[mt][r] + fbv;
                rsum[mt][r] += fu*rwv;
                msum[mt][r] += fu*mwv;
            }
    }
#pragma unroll
    for (int mt=0;mt<2;mt++)
#pragma unroll
        for (int r=0;r<4;r++){
#pragma unroll
            for (int off=1; off<16; off<<=1){
                rsum[mt][r] += __shfl_xor(rsum[mt][r], off);
                msum[mt][r] += __shfl_xor(msum[mt][r], off);
            }
            if (c==0){
                rpart[w][mt*16 + quad*4 + r] = rsum[mt][r];
                mpart[w][mt*16 + quad*4 + r] = msum[mt][r];
            }
        }
    __syncthreads();
    if (tid < 32){
        int s = tid;
        float rs = rb[0], ms = mb[0];
#pragma unroll
        for (int ww=0; ww<4; ww++){ rs += rpart[ww][s]; ms += mpart[ww][s]; }
        outp[s0+s] = rs;
        outp[2048 + s0 + s] = sigm(ms);
    }
}

extern "C" void kernel_launch(void* const* d_in, const int* in_sizes, int n_in,
                              void* d_out, int out_size, void* d_ws, size_t ws_size,
                              hipStream_t stream) {
    const float* sf    = (const float*)d_in[0];
    const int*   sec   = (const int*)  d_in[1];
    const int*   adj   = (const int*)  d_in[2];
    const float* g1Wih = (const float*)d_in[3];
    const float* g1Whh = (const float*)d_in[4];
    const float* g1bih = (const float*)d_in[5];
    const float* g1bhh = (const float*)d_in[6];
    const float* a1w   = (const float*)d_in[7];
    const float* a1b   = (const float*)d_in[8];
    const float* giW   = (const float*)d_in[9];
    const float* gia   = (const float*)d_in[10];
    const float* ggWih = (const float*)d_in[11];
    const float* ggbih = (const float*)d_in[13];
    const float* ggbhh = (const float*)d_in[14];
    const float* gaWih = (const float*)d_in[17];
    const float* gaWhh = (const float*)d_in[18];
    const float* gabih = (const float*)d_in[19];
    const float* gabhh = (const float*)d_in[20];
    const float* aaw   = (const float*)d_in[21];
    const float* aab   = (const float*)d_in[22];
    const float* geW   = (const float*)d_in[23];
    const float* gea   = (const float*)d_in[24];
    const float* fw    = (const float*)d_in[25];
    const float* fb    = (const float*)d_in[26];
    const float* rw    = (const float*)d_in[27];
    const float* rb    = (const float*)d_in[28];
    const float* mw    = (const float*)d_in[29];
    const float* mb    = (const float*)d_in[30];

    char* p = (char*)d_ws;
    f16*   shrt16 = (f16*)p;   p += (size_t)65536*128*2;
    f16*   lg16   = (f16*)p;   p += (size_t)262144*2;
    f16*   lg_s   = (f16*)p;   p += (size_t)262144*2;
    f16*   la16   = (f16*)p;   p += (size_t)262144*2;
    f16*   Whs    = (f16*)p;   p += (size_t)262144*2;
    f16*   intra_s= (f16*)p;   p += (size_t)262144*2;
    f16*   Wcat1  = (f16*)p;   p += (size_t)512*160*2;
    f16*   WcatA  = (f16*)p;   p += (size_t)512*256*2;
    f16*   WT     = (f16*)p;   p += (size_t)16384*2;
    f16*   fwT    = (f16*)p;   p += (size_t)49152*2;
    f16*   ggW16  = (f16*)p;   p += (size_t)49152*2;
    float* el     = (float*)p; p += 2048*4;
    float* ers    = (float*)p; p += 2048*4;
    float* secf   = (float*)p; p += 2048*4;
    float* seco   = (float*)p; p += 2048*4;
    int*   memflat= (int*)p;   p += 2048*4;
    int*   cnt    = (int*)p;   p += 16*4;
    int*   basep  = (int*)p;   p += 16*4;

    // 0. weight prep + bucketing
    prep_kernel<<<865,256,0,stream>>>(g1Wih, g1Whh, gaWih, gaWhh, giW, fw, ggWih, sec,
                                      Wcat1, WcatA, WT, fwT, ggW16, memflat, cnt, basep);
    // 1. short GRU+attn (65536 windows, T=5), M=64/block, xs dbuf (48KB LDS)
    gru_short<<<1024,512,0,stream>>>(sf, Wcat1, g1bih, g1bhh, a1w, a1b, shrt16);
    // 2. la GRU+attn + gat_prep merged
    la_gatprep<<<320,512,0,stream>>>(shrt16, WcatA, gabih, gabhh, aaw, aab, la16,
                                     WT, gia, memflat, Whs, ers, el);
    // 3. intra-sector GAT (sorted rows) -> intra_s
    gat_intra_mem_kernel<<<512,256,0,stream>>>(Whs, ers, el, sec, cnt, basep, memflat,
                                               intra_s, 2048);
    // 4. lg (T=1 GRU) via MFMA over sorted rows -> lg_s + lg16
    lg_mfma_sorted<<<64,256,0,stream>>>(intra_s, ggW16, ggbih, ggbhh, memflat, lg16, lg_s);
    // 5a. sector means over sorted lg_s
    sector_mean_sorted<<<16,128,0,stream>>>(lg_s, cnt, basep, secf);
    // 5b. inter-sector GAT (tiny)
    gat_inter_kernel<<<1,256,0,stream>>>(secf, adj, geW, gea, seco);
    // 6. fusion + heads
    fused_mfma<<<64,256,0,stream>>>(lg16, la16, seco, sec, fwT, fb, rw, rb, mw, mb, (float*)d_out);
}